// Round 3
// baseline (1252.887 us; speedup 1.0000x reference)
//
#include <hip/hip_runtime.h>
#include <math.h>

// ---------------------------------------------------------------------------
// TreeEnergyLoss on MI355X.
// softmax -> [k_edges: parallel chunked f64 edge distances via LDS-upsampled
// embeddings] -> [k_structure2: chunk-sum (fixed order) + Boruvka MST under
// strict (dist,edge-idx) order == reference's stable Kruskal + frontier BFS]
// -> two-pass tree filter -> ROI-masked L1 loss.
// Serial latency-bound kernels (structure, filters) run as ONE WAVE per block:
// s_barrier with a single resident wave is ~free, so the ~500 barrier-separated
// tiny segments stop paying multi-wave sync + drain costs.
// ---------------------------------------------------------------------------

#define HH 48
#define WW 48
#define NN (HH*WW)          // 2304 nodes
#define EHH (HH*(WW-1))     // 2256 horizontal edges
#define EEE (2*EHH)         // 4512 edges
#define BB 8
#define KK 4
#define TPB 256
#define TPS 64              // single-wave kernels
#define NE_PT ((EEE+TPB-1)/TPB)

// per-problem structure record in ws (ints): parent | wgt | order | levelStart | depth
#define SSTRIDE_W (4*NN+8)
#define P_OFF 0
#define W_OFF NN
#define O_OFF (2*NN)
#define L_OFF (3*NN)
#define D_OFF (4*NN+2)

struct Tap { int o00,o01,o10,o11; float w00,w01,w10,w11; };

__device__ __forceinline__ Tap mk_tap(int r,int c,int sh,int sw){
  float sy=(float)sh/48.0f, sx=(float)sw/48.0f;          // exact (pow2 ratios)
  float ys=fmaxf(((float)r+0.5f)*sy-0.5f,0.0f);
  float xs=fmaxf(((float)c+0.5f)*sx-0.5f,0.0f);
  int y0=(int)ys; if(y0>sh-1) y0=sh-1;
  int x0=(int)xs; if(x0>sw-1) x0=sw-1;
  int y1=y0+1; if(y1>sh-1) y1=sh-1;
  int x1=x0+1; if(x1>sw-1) x1=sw-1;
  float wy=ys-(float)y0, wx=xs-(float)x0;
  Tap t;
  t.o00=y0*sw+x0; t.o01=y0*sw+x1; t.o10=y1*sw+x0; t.o11=y1*sw+x1;
  t.w00=(1.0f-wy)*(1.0f-wx); t.w01=(1.0f-wy)*wx;
  t.w10=wy*(1.0f-wx);        t.w11=wy*wx;
  return t;
}

__device__ __forceinline__ float tap_val(const float* __restrict__ p, const Tap& t){
  return t.w00*p[t.o00]+t.w01*p[t.o01]+t.w10*p[t.o10]+t.w11*p[t.o11];
}

// numpy edge order: horizontal (row-major) first, then vertical.
__device__ __forceinline__ void edge_uv(int e,int& u,int& v){
  if(e<EHH){ int r=e/(WW-1); int c=e-r*(WW-1); u=r*WW+c; v=u+1; }
  else     { int t=e-EHH; u=t; v=t+WW; }
}

__device__ __forceinline__ void pick_src(int f, const float* lowf, const float* hf1,
                                         const float* hf2, const float* hf3,
                                         const float*& src, int& sh, int& C){
  if(f==0){src=lowf; sh=192; C=3;}
  else if(f==1){src=hf1; sh=24; C=512;}
  else if(f==2){src=hf2; sh=12; C=512;}
  else        {src=hf3; sh=6;  C=512;}
}

// ---------------------------------------------------------------------------
__global__ __launch_bounds__(TPB) void k_prob(const float* __restrict__ preds,
                                              float* __restrict__ probf){
  int t=blockIdx.x*TPB+threadIdx.x;
  if(t>=BB*NN) return;
  int b=t/NN, i=t-b*NN;
  const float* p=preds+(size_t)b*KK*NN+i;
  float x0=p[0],x1=p[NN],x2=p[2*NN],x3=p[3*NN];
  float mx=fmaxf(fmaxf(x0,x1),fmaxf(x2,x3));
  float e0=expf(x0-mx),e1=expf(x1-mx),e2=expf(x2-mx),e3=expf(x3-mx);
  float s=((e0+e1)+(e2+e3));
  float* q=probf+(size_t)b*KK*NN+i;
  q[0]=e0/s; q[NN]=e1/s; q[2*NN]=e2/s; q[3*NN]=e3/s;
}

// ---------------------------------------------------------------------------
// Parallel edge-distance partials.  One block = (problem, channel-chunk).
__global__ __launch_bounds__(TPB) void k_edges(
  const float* __restrict__ lowf, const float* __restrict__ hf1,
  const float* __restrict__ hf2, const float* __restrict__ hf3,
  double* __restrict__ pd, int nchunk)
{
  __shared__ float up[8*NN];   // 73728 B
  const int tid=threadIdx.x;
  int pidx, chunk;
  if(blockIdx.x<8){ pidx=blockIdx.x; chunk=0; }
  else { int t=blockIdx.x-8; pidx=8+t/nchunk; chunk=t%nchunk; }
  const int f=pidx>>3, b=pidx&7;
  const float* src; int sh,C;
  pick_src(f,lowf,hf1,hf2,hf3,src,sh,C);
  const int shw=sh*sh;
  const float* srcb=src+(size_t)b*C*shw;
  const int cpc=(f==0)?3:(512/nchunk);
  const int c_begin=chunk*cpc;
  const int c_end=(c_begin+cpc<C)?(c_begin+cpc):C;

  double acc[NE_PT];
  #pragma unroll
  for(int j=0;j<NE_PT;j++) acc[j]=0.0;

  for(int c0=c_begin;c0<c_end;c0+=8){
    const int nc=(c_end-c0<8)?(c_end-c0):8;
    __syncthreads();               // protect previous sub-stage reads
    for(int i=tid;i<NN;i+=TPB){
      Tap t=mk_tap(i/WW,i-(i/WW)*WW,sh,sh);
      const float* pl=srcb+(size_t)c0*shw;
      for(int c=0;c<nc;c++) up[c*NN+i]=tap_val(pl+(size_t)c*shw,t);
    }
    __syncthreads();
    #pragma unroll
    for(int j=0;j<NE_PT;j++){
      int e=tid+j*TPB;
      if(e<EEE){
        int u,v; edge_uv(e,u,v);
        double s=acc[j];
        for(int c=0;c<nc;c++){
          double d=(double)up[c*NN+u]-(double)up[c*NN+v];
          s=fma(d,d,s);
        }
        acc[j]=s;
      }
    }
  }
  #pragma unroll
  for(int j=0;j<NE_PT;j++){
    int e=tid+j*TPB;
    if(e<EEE) pd[((size_t)pidx*nchunk+chunk)*EEE+e]=acc[j];
  }
}

// ---------------------------------------------------------------------------
// SINGLE-WAVE kernel. One workgroup (64 threads) per (forest,batch):
// chunk-sum, Boruvka MST, frontier BFS (order[] + levelStart[]), wgt.
__global__ __launch_bounds__(TPS) void k_structure2(
  const double* __restrict__ pd, int nchunk, int* __restrict__ sbase)
{
  __shared__ double dkey[EEE];                  // 36096 B
  __shared__ unsigned long long bestd[NN];      // 18432 B
  __shared__ int comp[NN];
  __shared__ int lnk[NN];
  __shared__ int beste[NN];
  __shared__ int parentN[NN];
  __shared__ int ordS[NN];
  __shared__ int lsS[NN+2];
  __shared__ unsigned char mstf[EEE];
  __shared__ int flags[4];

  const int tid=threadIdx.x;
  const int pidx=blockIdx.x;
  const int f=pidx>>3;
  const float sigma=(f==0)?0.02f:1.0f;

  int* sp=sbase+(size_t)pidx*SSTRIDE_W;
  int* g_parent=sp+P_OFF;
  float* g_wgt=(float*)(sp+W_OFF);
  int* g_order=sp+O_OFF;
  int* g_ls=sp+L_OFF;

  // ---- gather edge distances: fixed chunk order (deterministic) ----
  const int nck=(f==0)?1:nchunk;
  for(int e=tid;e<EEE;e+=TPS){
    const double* p=pd+((size_t)pidx*nchunk)*EEE+e;
    double s=0.0;
    for(int k=0;k<nck;k++) s+=p[(size_t)k*EEE];
    dkey[e]=s;
  }
  for(int i=tid;i<NN;i+=TPS) comp[i]=i;
  for(int e=tid;e<EEE;e+=TPS) mstf[e]=0;
  __syncthreads();

  // ---- Boruvka: unique MST under strict (dist_bits, edge_index) order ----
  for(int round=0;round<24;++round){
    for(int i=tid;i<NN;i+=TPS){ bestd[i]=~0ull; beste[i]=0x7fffffff; lnk[i]=i; }
    __syncthreads();
    for(int e=tid;e<EEE;e+=TPS){
      int u,v; edge_uv(e,u,v);
      int cu=comp[u], cv=comp[v];
      if(cu!=cv){
        unsigned long long db=(unsigned long long)__double_as_longlong(dkey[e]);
        atomicMin(&bestd[cu],db);
        atomicMin(&bestd[cv],db);
      }
    }
    __syncthreads();
    for(int e=tid;e<EEE;e+=TPS){
      int u,v; edge_uv(e,u,v);
      int cu=comp[u], cv=comp[v];
      if(cu!=cv){
        unsigned long long db=(unsigned long long)__double_as_longlong(dkey[e]);
        if(db==bestd[cu]) atomicMin(&beste[cu],e);
        if(db==bestd[cv]) atomicMin(&beste[cv],e);
      }
    }
    __syncthreads();
    // hook (mutual pair resolved toward smaller id; mutual => SAME edge since order strict)
    for(int i=tid;i<NN;i+=TPS){
      if(comp[i]==i && beste[i]!=0x7fffffff){
        int e=beste[i]; int u,v; edge_uv(e,u,v);
        int cu=comp[u], cv=comp[v];
        int other=(cu==i)?cv:cu;
        bool mutual=(beste[other]==e);
        if(!mutual || other<i){ lnk[i]=other; mstf[e]=1; }
      }
    }
    __syncthreads();
    // pointer jumping to full compression
    for(;;){
      if(tid==0) flags[0]=0;
      __syncthreads();
      for(int i=tid;i<NN;i+=TPS){
        int a=lnk[i]; int a2=lnk[a];
        if(a!=a2){ lnk[i]=a2; flags[0]=1; }
      }
      __syncthreads();
      int done=flags[0];
      __syncthreads();
      if(!done) break;
    }
    for(int i=tid;i<NN;i+=TPS) comp[i]=lnk[comp[i]];
    __syncthreads();
    if(tid==0) flags[1]=0;
    __syncthreads();
    for(int i=tid;i<NN;i+=TPS) if(comp[i]==i) atomicAdd(&flags[1],1);
    __syncthreads();
    int nc=flags[1];
    __syncthreads();
    if(nc<=1) break;
  }

  // ---- frontier BFS from node 0: builds order[] + levelStart[] directly ----
  for(int i=tid;i<NN;i+=TPS) lnk[i]=0;          // lnk reused as visited
  __syncthreads();
  if(tid==0){ lnk[0]=1; parentN[0]=0; ordS[0]=0; lsS[0]=0; lsS[1]=1; flags[3]=1; }
  __syncthreads();
  int depth=0;
  for(int l=0;;++l){
    int s=lsS[l], e2=lsS[l+1];
    for(int k=s+tid;k<e2;k+=TPS){
      int i=ordS[k];
      int r=i/WW, c=i-r*WW;
      if(c>0    && mstf[r*(WW-1)+c-1]   && !lnk[i-1]) { lnk[i-1]=1;  parentN[i-1]=i;  int p2=atomicAdd(&flags[3],1); ordS[p2]=i-1; }
      if(c<WW-1 && mstf[r*(WW-1)+c]     && !lnk[i+1]) { lnk[i+1]=1;  parentN[i+1]=i;  int p2=atomicAdd(&flags[3],1); ordS[p2]=i+1; }
      if(r>0    && mstf[EHH+(r-1)*WW+c] && !lnk[i-WW]){ lnk[i-WW]=1; parentN[i-WW]=i; int p2=atomicAdd(&flags[3],1); ordS[p2]=i-WW; }
      if(r<HH-1 && mstf[EHH+r*WW+c]     && !lnk[i+WW]){ lnk[i+WW]=1; parentN[i+WW]=i; int p2=atomicAdd(&flags[3],1); ordS[p2]=i+WW; }
    }
    __syncthreads();
    int tail=flags[3];
    if(tid==0) lsS[l+2]=tail;
    __syncthreads();
    if(tail==lsS[l+1]){ depth=l; break; }
  }

  // ---- wgt[i] = exp(-dist(i,parent)/sigma) ----
  for(int i=tid;i<NN;i+=TPS){
    int p=parentN[i];
    int r=i/WW, c=i-r*WW;
    int e=-1;
    if(p==i+1)      e=r*(WW-1)+c;
    else if(p==i-1) e=r*(WW-1)+(c-1);
    else if(p==i+WW)e=EHH+i;
    else if(p==i-WW)e=EHH+p;
    g_wgt[i]=(e<0)?1.0f:expf(-(float)dkey[e]/sigma);
    g_parent[i]=p;
    g_order[i]=ordS[i];
  }
  for(int i=tid;i<depth+2;i+=TPS) g_ls[i]=lsS[i];
  if(tid==0) sp[D_OFF]=depth;
}

// ---------------------------------------------------------------------------
// SINGLE-WAVE tree filter, forest 0 (input: softmax probs; output: AS).
__global__ __launch_bounds__(TPS) void k_filter0(
  const float* __restrict__ probf, const int* __restrict__ sbase,
  float* __restrict__ AS)
{
  __shared__ float A[(KK+1)*NN];
  __shared__ float wgtS[NN];
  __shared__ int parS[NN];
  __shared__ int ordS[NN];
  __shared__ int lsS[NN+2];
  const int tid=threadIdx.x;
  const int b=blockIdx.x;
  const int* sp=sbase+(size_t)b*SSTRIDE_W;
  const int D=sp[D_OFF];
  // vectorized fills
  {
    const float4* pf4=(const float4*)(probf+(size_t)b*KK*NN);
    float4* A4=(float4*)A;
    for(int t=tid;t<(KK*NN)/4;t+=TPS) A4[t]=pf4[t];
    for(int t=KK*NN+tid;t<(KK+1)*NN;t+=TPS) A[t]=1.0f;
    const int4* p4=(const int4*)(sp+P_OFF);
    const int4* w4=(const int4*)(sp+W_OFF);
    const int4* o4=(const int4*)(sp+O_OFF);
    int4* parS4=(int4*)parS; int4* wgtS4=(int4*)wgtS; int4* ordS4=(int4*)ordS;
    for(int t=tid;t<NN/4;t+=TPS){ parS4[t]=p4[t]; wgtS4[t]=w4[t]; ordS4[t]=o4[t]; }
    for(int i=tid;i<D+2;i+=TPS) lsS[i]=sp[L_OFF+i];
  }
  __syncthreads();
  for(int l=D;l>=1;--l){
    int s=lsS[l], e2=lsS[l+1];
    for(int k=s+tid;k<e2;k+=TPS){
      int i=ordS[k]; int p=parS[i]; float w=wgtS[i];
      #pragma unroll
      for(int c=0;c<=KK;c++) atomicAdd(&A[c*NN+p], w*A[c*NN+i]);
    }
    __syncthreads();
  }
  for(int l=1;l<=D;++l){
    int s=lsS[l], e2=lsS[l+1];
    for(int k=s+tid;k<e2;k+=TPS){
      int i=ordS[k]; int p=parS[i]; float w=wgtS[i];
      #pragma unroll
      for(int c=0;c<=KK;c++){
        float a=A[c*NN+i];
        A[c*NN+i]=a+w*(A[c*NN+p]-w*a);
      }
    }
    __syncthreads();
  }
  {
    float4* AS4=(float4*)(AS+(size_t)b*KK*NN);
    const float4* A4=(const float4*)A;
    for(int t=tid;t<(KK*NN)/4;t+=TPS){
      int i4=t%(NN/4);
      float4 a=A4[t], d=A4[KK*(NN/4)+i4];
      float4 r; r.x=a.x/d.x; r.y=a.y/d.y; r.z=a.z/d.z; r.w=a.w/d.w;
      AS4[t]=r;
    }
  }
}

// ---------------------------------------------------------------------------
// SINGLE-WAVE tree filter, forests 1..3 (input: AS) + ROI-masked L1 partial.
__global__ __launch_bounds__(TPS) void k_filter123(
  const float* __restrict__ AS, const float* __restrict__ probf,
  const float* __restrict__ rois, const int* __restrict__ sbase,
  float* __restrict__ partials)
{
  __shared__ float A[(KK+1)*NN];
  __shared__ float wgtS[NN];
  __shared__ int parS[NN];
  __shared__ int ordS[NN];
  __shared__ int lsS[NN+2];
  const int tid=threadIdx.x;
  const int fm1=blockIdx.x/BB, b=blockIdx.x%BB;
  const int pidx=(fm1+1)*BB+b;
  const int* sp=sbase+(size_t)pidx*SSTRIDE_W;
  const int D=sp[D_OFF];
  {
    const float4* pf4=(const float4*)(AS+(size_t)b*KK*NN);
    float4* A4=(float4*)A;
    for(int t=tid;t<(KK*NN)/4;t+=TPS) A4[t]=pf4[t];
    for(int t=KK*NN+tid;t<(KK+1)*NN;t+=TPS) A[t]=1.0f;
    const int4* p4=(const int4*)(sp+P_OFF);
    const int4* w4=(const int4*)(sp+W_OFF);
    const int4* o4=(const int4*)(sp+O_OFF);
    int4* parS4=(int4*)parS; int4* wgtS4=(int4*)wgtS; int4* ordS4=(int4*)ordS;
    for(int t=tid;t<NN/4;t+=TPS){ parS4[t]=p4[t]; wgtS4[t]=w4[t]; ordS4[t]=o4[t]; }
    for(int i=tid;i<D+2;i+=TPS) lsS[i]=sp[L_OFF+i];
  }
  __syncthreads();
  for(int l=D;l>=1;--l){
    int s=lsS[l], e2=lsS[l+1];
    for(int k=s+tid;k<e2;k+=TPS){
      int i=ordS[k]; int p=parS[i]; float w=wgtS[i];
      #pragma unroll
      for(int c=0;c<=KK;c++) atomicAdd(&A[c*NN+p], w*A[c*NN+i]);
    }
    __syncthreads();
  }
  for(int l=1;l<=D;++l){
    int s=lsS[l], e2=lsS[l+1];
    for(int k=s+tid;k<e2;k+=TPS){
      int i=ordS[k]; int p=parS[i]; float w=wgtS[i];
      #pragma unroll
      for(int c=0;c<=KK;c++){
        float a=A[c*NN+i];
        A[c*NN+i]=a+w*(A[c*NN+p]-w*a);
      }
    }
    __syncthreads();
  }
  float part=0.0f;
  for(int i=tid;i<NN;i+=TPS){
    int r=i/WW, c2=i-r*WW;
    float roi=rois[(size_t)b*(192*192)+(4*r)*192+(4*c2)];
    float den=A[KK*NN+i];
    float s=0.0f;
    #pragma unroll
    for(int c=0;c<KK;c++){
      float ask=A[c*NN+i]/den;
      s+=fabsf(probf[(size_t)b*KK*NN+c*NN+i]-ask);
    }
    part+=roi*s;
  }
  #pragma unroll
  for(int s2=32;s2>0;s2>>=1) part+=__shfl_down(part,s2,64);
  if(tid==0) partials[blockIdx.x]=part;
}

// ---------------------------------------------------------------------------
__global__ __launch_bounds__(TPB) void k_final(const float* __restrict__ rois,
    const float* __restrict__ partials, const float* __restrict__ wt,
    float* __restrict__ out)
{
  __shared__ float red[TPB];
  const int tid=threadIdx.x;
  float n=0.0f;
  for(int t=tid;t<BB*NN;t+=TPB){
    int b=t/NN, i=t-b*NN; int r=i/WW, c=i-r*WW;
    n += rois[(size_t)b*(192*192)+(4*r)*192+(4*c)];
  }
  red[tid]=n; __syncthreads();
  for(int s=TPB/2;s>0;s>>=1){ if(tid<s) red[tid]+=red[tid+s]; __syncthreads(); }
  if(tid==0){
    float loss=0.0f;
    for(int j=0;j<3*BB;j++) loss+=partials[j];
    float N=red[0];
    out[0]=wt[0]*((N>0.0f)?(loss/N):loss);
  }
}

// ---------------------------------------------------------------------------
extern "C" void kernel_launch(void* const* d_in, const int* in_sizes, int n_in,
                              void* d_out, int out_size, void* d_ws, size_t ws_size,
                              hipStream_t stream) {
  (void)in_sizes; (void)n_in; (void)out_size;
  const float* preds=(const float*)d_in[0];
  const float* lowf =(const float*)d_in[1];
  const float* hf1  =(const float*)d_in[2];
  const float* hf2  =(const float*)d_in[3];
  const float* hf3  =(const float*)d_in[4];
  const float* rois =(const float*)d_in[5];
  const float* wt   =(const float*)d_in[6];
  float* out=(float*)d_out;

  char* ws=(char*)d_ws;
  float* partials=(float*)ws;                                   // 24 floats
  float* probf=(float*)(ws+256);                                // B*K*NN
  float* AS   =(float*)(ws+256+(size_t)BB*KK*NN*4);             // B*K*NN
  int*   sbase=(int*)  (ws+256+(size_t)2*BB*KK*NN*4);           // 32*SSTRIDE_W ints
  size_t pd_off=256+(size_t)2*BB*KK*NN*4+(size_t)32*SSTRIDE_W*4; // 8-aligned
  double* pd=(double*)(ws+pd_off);

  int nchunk=16;
  while(nchunk>1 && pd_off+(size_t)32*nchunk*EEE*8>ws_size) nchunk>>=1;

  k_prob<<<(BB*NN+TPB-1)/TPB,TPB,0,stream>>>(preds,probf);
  k_edges<<<8+24*nchunk,TPB,0,stream>>>(lowf,hf1,hf2,hf3,pd,nchunk);
  k_structure2<<<32,TPS,0,stream>>>(pd,nchunk,sbase);
  k_filter0<<<BB,TPS,0,stream>>>(probf,sbase,AS);
  k_filter123<<<3*BB,TPS,0,stream>>>(AS,probf,rois,sbase,partials);
  k_final<<<1,TPB,0,stream>>>(rois,partials,wt,out);
}

// Round 4
// 813.687 us; speedup vs baseline: 1.5398x; 1.5398x over previous
//
#include <hip/hip_runtime.h>
#include <math.h>

// ---------------------------------------------------------------------------
// TreeEnergyLoss on MI355X.
// softmax -> k_edges (parallel chunked f64 edge distances via LDS-upsampled
// embeddings) -> k_boruvka (512t: chunk-sum + Boruvka MST under strict
// (dist,edge-idx) order == reference's stable Kruskal; racy barrier-free
// pointer jumping) -> k_bfs (1 wave: frontier BFS -> parent/order/levels/wgt)
// -> single-wave two-pass tree filters -> ROI-masked L1 loss.
// Phase->width mapping from R3 post-mortem: edge sweeps are LDS-latency-chain
// bound (want 8 waves); BFS/filter levels are tiny-frontier (want 1 wave).
// ---------------------------------------------------------------------------

#define HH 48
#define WW 48
#define NN (HH*WW)          // 2304 nodes
#define EHH (HH*(WW-1))     // 2256 horizontal edges
#define EEE (2*EHH)         // 4512 edges
#define BB 8
#define KK 4
#define TPB 256
#define TPS 64              // single-wave kernels
#define TPW 512             // boruvka kernel
#define NE_PT ((EEE+TPB-1)/TPB)

// per-problem structure record in ws (ints): parent | wgt | order | levelStart | depth
#define SSTRIDE_W (4*NN+8)
#define P_OFF 0
#define W_OFF NN
#define O_OFF (2*NN)
#define L_OFF (3*NN)
#define D_OFF (4*NN+2)

struct Tap { int o00,o01,o10,o11; float w00,w01,w10,w11; };

__device__ __forceinline__ Tap mk_tap(int r,int c,int sh,int sw){
  float sy=(float)sh/48.0f, sx=(float)sw/48.0f;          // exact (pow2 ratios)
  float ys=fmaxf(((float)r+0.5f)*sy-0.5f,0.0f);
  float xs=fmaxf(((float)c+0.5f)*sx-0.5f,0.0f);
  int y0=(int)ys; if(y0>sh-1) y0=sh-1;
  int x0=(int)xs; if(x0>sw-1) x0=sw-1;
  int y1=y0+1; if(y1>sh-1) y1=sh-1;
  int x1=x0+1; if(x1>sw-1) x1=sw-1;
  float wy=ys-(float)y0, wx=xs-(float)x0;
  Tap t;
  t.o00=y0*sw+x0; t.o01=y0*sw+x1; t.o10=y1*sw+x0; t.o11=y1*sw+x1;
  t.w00=(1.0f-wy)*(1.0f-wx); t.w01=(1.0f-wy)*wx;
  t.w10=wy*(1.0f-wx);        t.w11=wy*wx;
  return t;
}

__device__ __forceinline__ float tap_val(const float* __restrict__ p, const Tap& t){
  return t.w00*p[t.o00]+t.w01*p[t.o01]+t.w10*p[t.o10]+t.w11*p[t.o11];
}

// numpy edge order: horizontal (row-major) first, then vertical.
__device__ __forceinline__ void edge_uv(int e,int& u,int& v){
  if(e<EHH){ int r=e/(WW-1); int c=e-r*(WW-1); u=r*WW+c; v=u+1; }
  else     { int t=e-EHH; u=t; v=t+WW; }
}

__device__ __forceinline__ void pick_src(int f, const float* lowf, const float* hf1,
                                         const float* hf2, const float* hf3,
                                         const float*& src, int& sh, int& C){
  if(f==0){src=lowf; sh=192; C=3;}
  else if(f==1){src=hf1; sh=24; C=512;}
  else if(f==2){src=hf2; sh=12; C=512;}
  else        {src=hf3; sh=6;  C=512;}
}

// ---------------------------------------------------------------------------
__global__ __launch_bounds__(TPB) void k_prob(const float* __restrict__ preds,
                                              float* __restrict__ probf){
  int t=blockIdx.x*TPB+threadIdx.x;
  if(t>=BB*NN) return;
  int b=t/NN, i=t-b*NN;
  const float* p=preds+(size_t)b*KK*NN+i;
  float x0=p[0],x1=p[NN],x2=p[2*NN],x3=p[3*NN];
  float mx=fmaxf(fmaxf(x0,x1),fmaxf(x2,x3));
  float e0=expf(x0-mx),e1=expf(x1-mx),e2=expf(x2-mx),e3=expf(x3-mx);
  float s=((e0+e1)+(e2+e3));
  float* q=probf+(size_t)b*KK*NN+i;
  q[0]=e0/s; q[NN]=e1/s; q[2*NN]=e2/s; q[3*NN]=e3/s;
}

// ---------------------------------------------------------------------------
// Parallel edge-distance partials.  One block = (problem, channel-chunk).
__global__ __launch_bounds__(TPB) void k_edges(
  const float* __restrict__ lowf, const float* __restrict__ hf1,
  const float* __restrict__ hf2, const float* __restrict__ hf3,
  double* __restrict__ pd, int nchunk)
{
  __shared__ float up[8*NN];   // 73728 B
  const int tid=threadIdx.x;
  int pidx, chunk;
  if(blockIdx.x<8){ pidx=blockIdx.x; chunk=0; }
  else { int t=blockIdx.x-8; pidx=8+t/nchunk; chunk=t%nchunk; }
  const int f=pidx>>3, b=pidx&7;
  const float* src; int sh,C;
  pick_src(f,lowf,hf1,hf2,hf3,src,sh,C);
  const int shw=sh*sh;
  const float* srcb=src+(size_t)b*C*shw;
  const int cpc=(f==0)?3:(512/nchunk);
  const int c_begin=chunk*cpc;
  const int c_end=(c_begin+cpc<C)?(c_begin+cpc):C;

  double acc[NE_PT];
  #pragma unroll
  for(int j=0;j<NE_PT;j++) acc[j]=0.0;

  for(int c0=c_begin;c0<c_end;c0+=8){
    const int nc=(c_end-c0<8)?(c_end-c0):8;
    __syncthreads();               // protect previous sub-stage reads
    for(int i=tid;i<NN;i+=TPB){
      Tap t=mk_tap(i/WW,i-(i/WW)*WW,sh,sh);
      const float* pl=srcb+(size_t)c0*shw;
      for(int c=0;c<nc;c++) up[c*NN+i]=tap_val(pl+(size_t)c*shw,t);
    }
    __syncthreads();
    #pragma unroll
    for(int j=0;j<NE_PT;j++){
      int e=tid+j*TPB;
      if(e<EEE){
        int u,v; edge_uv(e,u,v);
        double s=acc[j];
        for(int c=0;c<nc;c++){
          double d=(double)up[c*NN+u]-(double)up[c*NN+v];
          s=fma(d,d,s);
        }
        acc[j]=s;
      }
    }
  }
  #pragma unroll
  for(int j=0;j<NE_PT;j++){
    int e=tid+j*TPB;
    if(e<EEE) pd[((size_t)pidx*nchunk+chunk)*EEE+e]=acc[j];
  }
}

// ---------------------------------------------------------------------------
// 512-thread Boruvka per (forest,batch).  Outputs per-edge MST mask + weight.
__global__ __launch_bounds__(TPW) void k_boruvka(
  const double* __restrict__ pd, int nchunk,
  float* __restrict__ wgtEG, unsigned char* __restrict__ mstfG)
{
  __shared__ double dkey[EEE];                  // 36096 B
  __shared__ unsigned long long bestd[NN];      // 18432 B
  __shared__ int comp[NN];
  __shared__ int lnk[NN];
  __shared__ int beste[NN];
  __shared__ unsigned char mstf[EEE];
  __shared__ int flags[2];

  const int tid=threadIdx.x;
  const int pidx=blockIdx.x;
  const int f=pidx>>3;
  const float sigma=(f==0)?0.02f:1.0f;

  // ---- gather edge distances: fixed chunk order (deterministic) ----
  const int nck=(f==0)?1:nchunk;
  for(int e=tid;e<EEE;e+=TPW){
    const double* p=pd+((size_t)pidx*nchunk)*EEE+e;
    double s=0.0;
    for(int k=0;k<nck;k++) s+=p[(size_t)k*EEE];
    dkey[e]=s;
  }
  for(int i=tid;i<NN;i+=TPW) comp[i]=i;
  for(int e=tid;e<EEE;e+=TPW) mstf[e]=0;
  __syncthreads();

  // ---- Boruvka: unique MST under strict (dist_bits, edge_index) order ----
  for(int round=0;round<24;++round){
    for(int i=tid;i<NN;i+=TPW){ bestd[i]=~0ull; beste[i]=0x7fffffff; lnk[i]=i; }
    if(tid==0) flags[1]=0;
    __syncthreads();
    for(int e=tid;e<EEE;e+=TPW){
      int u,v; edge_uv(e,u,v);
      int cu=comp[u], cv=comp[v];
      if(cu!=cv){
        unsigned long long db=(unsigned long long)__double_as_longlong(dkey[e]);
        atomicMin(&bestd[cu],db);
        atomicMin(&bestd[cv],db);
      }
    }
    __syncthreads();
    for(int e=tid;e<EEE;e+=TPW){
      int u,v; edge_uv(e,u,v);
      int cu=comp[u], cv=comp[v];
      if(cu!=cv){
        unsigned long long db=(unsigned long long)__double_as_longlong(dkey[e]);
        if(db==bestd[cu]) atomicMin(&beste[cu],e);
        if(db==bestd[cv]) atomicMin(&beste[cv],e);
      }
    }
    __syncthreads();
    // hook (mutual pair resolved toward smaller id; mutual => SAME edge since order strict)
    for(int i=tid;i<NN;i+=TPW){
      if(comp[i]==i && beste[i]!=0x7fffffff){
        int e=beste[i]; int u,v; edge_uv(e,u,v);
        int cu=comp[u], cv=comp[v];
        int other=(cu==i)?cv:cu;
        bool mutual=(beste[other]==e);
        if(!mutual || other<i){ lnk[i]=other; mstf[e]=1; flags[1]=1; }
      }
    }
    __syncthreads();
    if(flags[1]==0) break;          // no hooks => forest complete
    // ---- racy barrier-free pointer jumping (monotone-convergent) ----
    {
      volatile int* vl=lnk;
      for(int it=0;it<12;++it){
        for(int i=tid;i<NN;i+=TPW){ int a=vl[i]; int b2=vl[a]; if(a!=b2) vl[i]=b2; }
      }
      // flagged verify passes until stable
      for(;;){
        if(tid==0) flags[0]=0;
        __syncthreads();
        for(int i=tid;i<NN;i+=TPW){
          int a=vl[i]; int b2=vl[a];
          if(a!=b2){ vl[i]=b2; flags[0]=1; }
        }
        __syncthreads();
        int ch=flags[0];
        __syncthreads();
        if(!ch) break;
      }
    }
    for(int i=tid;i<NN;i+=TPW) comp[i]=lnk[comp[i]];
    __syncthreads();
  }

  // ---- emit per-edge MST weight (pre-exp'd) + mask ----
  for(int e=tid;e<EEE;e+=TPW){
    unsigned char m=mstf[e];
    wgtEG[(size_t)pidx*EEE+e]=m?expf(-(float)dkey[e]/sigma):0.0f;
    mstfG[(size_t)pidx*EEE+e]=m;
  }
}

// ---------------------------------------------------------------------------
// SINGLE-WAVE frontier BFS: parent/order/levelStart/wgt -> sbase record.
__global__ __launch_bounds__(TPS) void k_bfs(
  const float* __restrict__ wgtEG, const unsigned char* __restrict__ mstfG,
  int* __restrict__ sbase)
{
  __shared__ float wE[EEE];          // 18048 B
  __shared__ unsigned char mstf[EEE];
  __shared__ int parentN[NN];
  __shared__ int ordS[NN];
  __shared__ int lsS[NN+2];
  __shared__ int vis[NN];
  __shared__ int flags[2];

  const int tid=threadIdx.x;
  const int pidx=blockIdx.x;
  int* sp=sbase+(size_t)pidx*SSTRIDE_W;
  int* g_parent=sp+P_OFF;
  float* g_wgt=(float*)(sp+W_OFF);
  int* g_order=sp+O_OFF;
  int* g_ls=sp+L_OFF;

  {
    const float4* w4=(const float4*)(wgtEG+(size_t)pidx*EEE);
    float4* wE4=(float4*)wE;
    for(int t=tid;t<EEE/4;t+=TPS) wE4[t]=w4[t];
    const int* m4=(const int*)(mstfG+(size_t)pidx*EEE);
    int* mstf4=(int*)mstf;
    for(int t=tid;t<EEE/4;t+=TPS) mstf4[t]=m4[t];
  }
  for(int i=tid;i<NN;i+=TPS) vis[i]=0;
  __syncthreads();
  if(tid==0){ vis[0]=1; parentN[0]=0; ordS[0]=0; lsS[0]=0; lsS[1]=1; flags[0]=1; }
  __syncthreads();
  int depth=0;
  for(int l=0;;++l){
    int s=lsS[l], e2=lsS[l+1];
    for(int k=s+tid;k<e2;k+=TPS){
      int i=ordS[k];
      int r=i/WW, c=i-r*WW;
      if(c>0    && mstf[r*(WW-1)+c-1]   && !vis[i-1]) { vis[i-1]=1;  parentN[i-1]=i;  int p2=atomicAdd(&flags[0],1); ordS[p2]=i-1; }
      if(c<WW-1 && mstf[r*(WW-1)+c]     && !vis[i+1]) { vis[i+1]=1;  parentN[i+1]=i;  int p2=atomicAdd(&flags[0],1); ordS[p2]=i+1; }
      if(r>0    && mstf[EHH+(r-1)*WW+c] && !vis[i-WW]){ vis[i-WW]=1; parentN[i-WW]=i; int p2=atomicAdd(&flags[0],1); ordS[p2]=i-WW; }
      if(r<HH-1 && mstf[EHH+r*WW+c]     && !vis[i+WW]){ vis[i+WW]=1; parentN[i+WW]=i; int p2=atomicAdd(&flags[0],1); ordS[p2]=i+WW; }
    }
    __syncthreads();
    int tail=flags[0];
    if(tid==0) lsS[l+2]=tail;
    __syncthreads();
    if(tail==lsS[l+1]){ depth=l; break; }
  }

  for(int i=tid;i<NN;i+=TPS){
    int p=parentN[i];
    int r=i/WW, c=i-r*WW;
    int e=-1;
    if(p==i+1)      e=r*(WW-1)+c;
    else if(p==i-1) e=r*(WW-1)+(c-1);
    else if(p==i+WW)e=EHH+i;
    else if(p==i-WW)e=EHH+p;
    g_wgt[i]=(e<0)?1.0f:wE[e];
    g_parent[i]=p;
    g_order[i]=ordS[i];
  }
  for(int i=tid;i<depth+2;i+=TPS) g_ls[i]=lsS[i];
  if(tid==0) sp[D_OFF]=depth;
}

// ---------------------------------------------------------------------------
// SINGLE-WAVE tree filter, forest 0 (input: softmax probs; output: AS).
__global__ __launch_bounds__(TPS) void k_filter0(
  const float* __restrict__ probf, const int* __restrict__ sbase,
  float* __restrict__ AS)
{
  __shared__ float A[(KK+1)*NN];
  __shared__ float wgtS[NN];
  __shared__ int parS[NN];
  __shared__ int ordS[NN];
  __shared__ int lsS[NN+2];
  const int tid=threadIdx.x;
  const int b=blockIdx.x;
  const int* sp=sbase+(size_t)b*SSTRIDE_W;
  const int D=sp[D_OFF];
  {
    const float4* pf4=(const float4*)(probf+(size_t)b*KK*NN);
    float4* A4=(float4*)A;
    for(int t=tid;t<(KK*NN)/4;t+=TPS) A4[t]=pf4[t];
    for(int t=KK*NN+tid;t<(KK+1)*NN;t+=TPS) A[t]=1.0f;
    const int4* p4=(const int4*)(sp+P_OFF);
    const int4* w4=(const int4*)(sp+W_OFF);
    const int4* o4=(const int4*)(sp+O_OFF);
    int4* parS4=(int4*)parS; int4* wgtS4=(int4*)wgtS; int4* ordS4=(int4*)ordS;
    for(int t=tid;t<NN/4;t+=TPS){ parS4[t]=p4[t]; wgtS4[t]=w4[t]; ordS4[t]=o4[t]; }
    for(int i=tid;i<D+2;i+=TPS) lsS[i]=sp[L_OFF+i];
  }
  __syncthreads();
  for(int l=D;l>=1;--l){
    int s=lsS[l], e2=lsS[l+1];
    for(int k=s+tid;k<e2;k+=TPS){
      int i=ordS[k]; int p=parS[i]; float w=wgtS[i];
      #pragma unroll
      for(int c=0;c<=KK;c++) atomicAdd(&A[c*NN+p], w*A[c*NN+i]);
    }
    __syncthreads();
  }
  for(int l=1;l<=D;++l){
    int s=lsS[l], e2=lsS[l+1];
    for(int k=s+tid;k<e2;k+=TPS){
      int i=ordS[k]; int p=parS[i]; float w=wgtS[i];
      #pragma unroll
      for(int c=0;c<=KK;c++){
        float a=A[c*NN+i];
        A[c*NN+i]=a+w*(A[c*NN+p]-w*a);
      }
    }
    __syncthreads();
  }
  {
    float4* AS4=(float4*)(AS+(size_t)b*KK*NN);
    const float4* A4=(const float4*)A;
    for(int t=tid;t<(KK*NN)/4;t+=TPS){
      int i4=t%(NN/4);
      float4 a=A4[t], d=A4[KK*(NN/4)+i4];
      float4 r; r.x=a.x/d.x; r.y=a.y/d.y; r.z=a.z/d.z; r.w=a.w/d.w;
      AS4[t]=r;
    }
  }
}

// ---------------------------------------------------------------------------
// SINGLE-WAVE tree filter, forests 1..3 (input: AS) + ROI-masked L1 partial.
__global__ __launch_bounds__(TPS) void k_filter123(
  const float* __restrict__ AS, const float* __restrict__ probf,
  const float* __restrict__ rois, const int* __restrict__ sbase,
  float* __restrict__ partials)
{
  __shared__ float A[(KK+1)*NN];
  __shared__ float wgtS[NN];
  __shared__ int parS[NN];
  __shared__ int ordS[NN];
  __shared__ int lsS[NN+2];
  const int tid=threadIdx.x;
  const int fm1=blockIdx.x/BB, b=blockIdx.x%BB;
  const int pidx=(fm1+1)*BB+b;
  const int* sp=sbase+(size_t)pidx*SSTRIDE_W;
  const int D=sp[D_OFF];
  {
    const float4* pf4=(const float4*)(AS+(size_t)b*KK*NN);
    float4* A4=(float4*)A;
    for(int t=tid;t<(KK*NN)/4;t+=TPS) A4[t]=pf4[t];
    for(int t=KK*NN+tid;t<(KK+1)*NN;t+=TPS) A[t]=1.0f;
    const int4* p4=(const int4*)(sp+P_OFF);
    const int4* w4=(const int4*)(sp+W_OFF);
    const int4* o4=(const int4*)(sp+O_OFF);
    int4* parS4=(int4*)parS; int4* wgtS4=(int4*)wgtS; int4* ordS4=(int4*)ordS;
    for(int t=tid;t<NN/4;t+=TPS){ parS4[t]=p4[t]; wgtS4[t]=w4[t]; ordS4[t]=o4[t]; }
    for(int i=tid;i<D+2;i+=TPS) lsS[i]=sp[L_OFF+i];
  }
  __syncthreads();
  for(int l=D;l>=1;--l){
    int s=lsS[l], e2=lsS[l+1];
    for(int k=s+tid;k<e2;k+=TPS){
      int i=ordS[k]; int p=parS[i]; float w=wgtS[i];
      #pragma unroll
      for(int c=0;c<=KK;c++) atomicAdd(&A[c*NN+p], w*A[c*NN+i]);
    }
    __syncthreads();
  }
  for(int l=1;l<=D;++l){
    int s=lsS[l], e2=lsS[l+1];
    for(int k=s+tid;k<e2;k+=TPS){
      int i=ordS[k]; int p=parS[i]; float w=wgtS[i];
      #pragma unroll
      for(int c=0;c<=KK;c++){
        float a=A[c*NN+i];
        A[c*NN+i]=a+w*(A[c*NN+p]-w*a);
      }
    }
    __syncthreads();
  }
  float part=0.0f;
  for(int i=tid;i<NN;i+=TPS){
    int r=i/WW, c2=i-r*WW;
    float roi=rois[(size_t)b*(192*192)+(4*r)*192+(4*c2)];
    float den=A[KK*NN+i];
    float s=0.0f;
    #pragma unroll
    for(int c=0;c<KK;c++){
      float ask=A[c*NN+i]/den;
      s+=fabsf(probf[(size_t)b*KK*NN+c*NN+i]-ask);
    }
    part+=roi*s;
  }
  #pragma unroll
  for(int s2=32;s2>0;s2>>=1) part+=__shfl_down(part,s2,64);
  if(tid==0) partials[blockIdx.x]=part;
}

// ---------------------------------------------------------------------------
__global__ __launch_bounds__(TPB) void k_final(const float* __restrict__ rois,
    const float* __restrict__ partials, const float* __restrict__ wt,
    float* __restrict__ out)
{
  __shared__ float red[TPB];
  const int tid=threadIdx.x;
  float n=0.0f;
  for(int t=tid;t<BB*NN;t+=TPB){
    int b=t/NN, i=t-b*NN; int r=i/WW, c=i-r*WW;
    n += rois[(size_t)b*(192*192)+(4*r)*192+(4*c)];
  }
  red[tid]=n; __syncthreads();
  for(int s=TPB/2;s>0;s>>=1){ if(tid<s) red[tid]+=red[tid+s]; __syncthreads(); }
  if(tid==0){
    float loss=0.0f;
    for(int j=0;j<3*BB;j++) loss+=partials[j];
    float N=red[0];
    out[0]=wt[0]*((N>0.0f)?(loss/N):loss);
  }
}

// ---------------------------------------------------------------------------
extern "C" void kernel_launch(void* const* d_in, const int* in_sizes, int n_in,
                              void* d_out, int out_size, void* d_ws, size_t ws_size,
                              hipStream_t stream) {
  (void)in_sizes; (void)n_in; (void)out_size;
  const float* preds=(const float*)d_in[0];
  const float* lowf =(const float*)d_in[1];
  const float* hf1  =(const float*)d_in[2];
  const float* hf2  =(const float*)d_in[3];
  const float* hf3  =(const float*)d_in[4];
  const float* rois =(const float*)d_in[5];
  const float* wt   =(const float*)d_in[6];
  float* out=(float*)d_out;

  char* ws=(char*)d_ws;
  float* partials=(float*)ws;                                     // 24 floats
  float* probf=(float*)(ws+256);                                  // B*K*NN
  float* AS   =(float*)(ws+256+(size_t)BB*KK*NN*4);               // B*K*NN
  int*   sbase=(int*)  (ws+256+(size_t)2*BB*KK*NN*4);             // 32*SSTRIDE_W ints
  size_t wE_off=256+(size_t)2*BB*KK*NN*4+(size_t)32*SSTRIDE_W*4;  // 1,770,752
  float* wgtEG=(float*)(ws+wE_off);                               // 32*EEE floats
  size_t mf_off=wE_off+(size_t)32*EEE*4;                          // 2,348,288
  unsigned char* mstfG=(unsigned char*)(ws+mf_off);               // 32*EEE bytes
  size_t pd_off=mf_off+(size_t)32*EEE;                            // 2,492,672 (8-aligned)
  double* pd=(double*)(ws+pd_off);

  int nchunk=16;
  while(nchunk>1 && pd_off+(size_t)32*nchunk*EEE*8>ws_size) nchunk>>=1;

  k_prob<<<(BB*NN+TPB-1)/TPB,TPB,0,stream>>>(preds,probf);
  k_edges<<<8+24*nchunk,TPB,0,stream>>>(lowf,hf1,hf2,hf3,pd,nchunk);
  k_boruvka<<<32,TPW,0,stream>>>(pd,nchunk,wgtEG,mstfG);
  k_bfs<<<32,TPS,0,stream>>>(wgtEG,mstfG,sbase);
  k_filter0<<<BB,TPS,0,stream>>>(probf,sbase,AS);
  k_filter123<<<3*BB,TPS,0,stream>>>(AS,probf,rois,sbase,partials);
  k_final<<<1,TPB,0,stream>>>(rois,partials,wt,out);
}

// Round 5
// 746.386 us; speedup vs baseline: 1.6786x; 1.0902x over previous
//
#include <hip/hip_runtime.h>
#include <math.h>

// ---------------------------------------------------------------------------
// TreeEnergyLoss on MI355X.
// softmax -> k_edges (parallel chunked f64 edge distances via LDS-upsampled
// embeddings) -> k_boruvka (512t: chunk-sum + Boruvka MST under strict
// (dist,edge-idx) order == reference's stable Kruskal; emits per-node adj
// mask + per-direction edge weights) -> k_bfs (1 wave: register-frontier
// ballot-compacted BFS, no vis array -- tree property makes child discovery
// race-free; emits packed (node,parent,w) int4 records + level starts)
// -> single-wave two-pass tree filters on packed records -> masked L1 loss.
// ---------------------------------------------------------------------------

#define HH 48
#define WW 48
#define NN (HH*WW)          // 2304 nodes
#define EHH (HH*(WW-1))     // 2256 horizontal edges
#define EEE (2*EHH)         // 4512 edges
#define BB 8
#define KK 4
#define TPB 256
#define TPS 64              // single-wave kernels
#define TPW 512             // boruvka kernel
#define NE_PT ((EEE+TPB-1)/TPB)

// per-problem structure record in ws (ints): packed int4[NN] | levelStart | depth
#define SSTRIDE_W (5*NN+8)
#define PK_OFF 0
#define L_OFF (4*NN)
#define D_OFF (5*NN+2)

struct Tap { int o00,o01,o10,o11; float w00,w01,w10,w11; };

__device__ __forceinline__ Tap mk_tap(int r,int c,int sh,int sw){
  float sy=(float)sh/48.0f, sx=(float)sw/48.0f;          // exact (pow2 ratios)
  float ys=fmaxf(((float)r+0.5f)*sy-0.5f,0.0f);
  float xs=fmaxf(((float)c+0.5f)*sx-0.5f,0.0f);
  int y0=(int)ys; if(y0>sh-1) y0=sh-1;
  int x0=(int)xs; if(x0>sw-1) x0=sw-1;
  int y1=y0+1; if(y1>sh-1) y1=sh-1;
  int x1=x0+1; if(x1>sw-1) x1=sw-1;
  float wy=ys-(float)y0, wx=xs-(float)x0;
  Tap t;
  t.o00=y0*sw+x0; t.o01=y0*sw+x1; t.o10=y1*sw+x0; t.o11=y1*sw+x1;
  t.w00=(1.0f-wy)*(1.0f-wx); t.w01=(1.0f-wy)*wx;
  t.w10=wy*(1.0f-wx);        t.w11=wy*wx;
  return t;
}

__device__ __forceinline__ float tap_val(const float* __restrict__ p, const Tap& t){
  return t.w00*p[t.o00]+t.w01*p[t.o01]+t.w10*p[t.o10]+t.w11*p[t.o11];
}

// numpy edge order: horizontal (row-major) first, then vertical.
__device__ __forceinline__ void edge_uv(int e,int& u,int& v){
  if(e<EHH){ int r=e/(WW-1); int c=e-r*(WW-1); u=r*WW+c; v=u+1; }
  else     { int t=e-EHH; u=t; v=t+WW; }
}

__device__ __forceinline__ void pick_src(int f, const float* lowf, const float* hf1,
                                         const float* hf2, const float* hf3,
                                         const float*& src, int& sh, int& C){
  if(f==0){src=lowf; sh=192; C=3;}
  else if(f==1){src=hf1; sh=24; C=512;}
  else if(f==2){src=hf2; sh=12; C=512;}
  else        {src=hf3; sh=6;  C=512;}
}

// ---------------------------------------------------------------------------
__global__ __launch_bounds__(TPB) void k_prob(const float* __restrict__ preds,
                                              float* __restrict__ probf){
  int t=blockIdx.x*TPB+threadIdx.x;
  if(t>=BB*NN) return;
  int b=t/NN, i=t-b*NN;
  const float* p=preds+(size_t)b*KK*NN+i;
  float x0=p[0],x1=p[NN],x2=p[2*NN],x3=p[3*NN];
  float mx=fmaxf(fmaxf(x0,x1),fmaxf(x2,x3));
  float e0=expf(x0-mx),e1=expf(x1-mx),e2=expf(x2-mx),e3=expf(x3-mx);
  float s=((e0+e1)+(e2+e3));
  float* q=probf+(size_t)b*KK*NN+i;
  q[0]=e0/s; q[NN]=e1/s; q[2*NN]=e2/s; q[3*NN]=e3/s;
}

// ---------------------------------------------------------------------------
// Parallel edge-distance partials.  One block = (problem, channel-chunk).
__global__ __launch_bounds__(TPB) void k_edges(
  const float* __restrict__ lowf, const float* __restrict__ hf1,
  const float* __restrict__ hf2, const float* __restrict__ hf3,
  double* __restrict__ pd, int nchunk)
{
  __shared__ float up[8*NN];   // 73728 B
  const int tid=threadIdx.x;
  int pidx, chunk;
  if(blockIdx.x<8){ pidx=blockIdx.x; chunk=0; }
  else { int t=blockIdx.x-8; pidx=8+t/nchunk; chunk=t%nchunk; }
  const int f=pidx>>3, b=pidx&7;
  const float* src; int sh,C;
  pick_src(f,lowf,hf1,hf2,hf3,src,sh,C);
  const int shw=sh*sh;
  const float* srcb=src+(size_t)b*C*shw;
  const int cpc=(f==0)?3:(512/nchunk);
  const int c_begin=chunk*cpc;
  const int c_end=(c_begin+cpc<C)?(c_begin+cpc):C;

  double acc[NE_PT];
  #pragma unroll
  for(int j=0;j<NE_PT;j++) acc[j]=0.0;

  for(int c0=c_begin;c0<c_end;c0+=8){
    const int nc=(c_end-c0<8)?(c_end-c0):8;
    __syncthreads();               // protect previous sub-stage reads
    for(int i=tid;i<NN;i+=TPB){
      Tap t=mk_tap(i/WW,i-(i/WW)*WW,sh,sh);
      const float* pl=srcb+(size_t)c0*shw;
      for(int c=0;c<nc;c++) up[c*NN+i]=tap_val(pl+(size_t)c*shw,t);
    }
    __syncthreads();
    #pragma unroll
    for(int j=0;j<NE_PT;j++){
      int e=tid+j*TPB;
      if(e<EEE){
        int u,v; edge_uv(e,u,v);
        double s=acc[j];
        for(int c=0;c<nc;c++){
          double d=(double)up[c*NN+u]-(double)up[c*NN+v];
          s=fma(d,d,s);
        }
        acc[j]=s;
      }
    }
  }
  #pragma unroll
  for(int j=0;j<NE_PT;j++){
    int e=tid+j*TPB;
    if(e<EEE) pd[((size_t)pidx*nchunk+chunk)*EEE+e]=acc[j];
  }
}

// ---------------------------------------------------------------------------
// 512-thread Boruvka per (forest,batch).
// Outputs per-node tree-adjacency mask (L,R,U,D bits) + per-direction weights.
__global__ __launch_bounds__(TPW) void k_boruvka(
  const double* __restrict__ pd, int nchunk,
  float4* __restrict__ adjwG, unsigned char* __restrict__ adjG)
{
  __shared__ double dkey[EEE];                  // 36096 B
  __shared__ unsigned long long bestd[NN];      // 18432 B
  __shared__ int comp[NN];
  __shared__ int lnk[NN];
  __shared__ int beste[NN];
  __shared__ unsigned char mstf[EEE];
  __shared__ int flags[2];

  const int tid=threadIdx.x;
  const int pidx=blockIdx.x;
  const int f=pidx>>3;
  const float sigma=(f==0)?0.02f:1.0f;

  // ---- gather edge distances: fixed chunk order (deterministic) ----
  const int nck=(f==0)?1:nchunk;
  for(int e=tid;e<EEE;e+=TPW){
    const double* p=pd+((size_t)pidx*nchunk)*EEE+e;
    double s=0.0;
    for(int k=0;k<nck;k++) s+=p[(size_t)k*EEE];
    dkey[e]=s;
  }
  for(int i=tid;i<NN;i+=TPW) comp[i]=i;
  for(int e=tid;e<EEE;e+=TPW) mstf[e]=0;
  __syncthreads();

  // ---- Boruvka: unique MST under strict (dist_bits, edge_index) order ----
  for(int round=0;round<24;++round){
    for(int i=tid;i<NN;i+=TPW){ bestd[i]=~0ull; beste[i]=0x7fffffff; lnk[i]=i; }
    if(tid==0) flags[1]=0;
    __syncthreads();
    for(int e=tid;e<EEE;e+=TPW){
      int u,v; edge_uv(e,u,v);
      int cu=comp[u], cv=comp[v];
      if(cu!=cv){
        unsigned long long db=(unsigned long long)__double_as_longlong(dkey[e]);
        atomicMin(&bestd[cu],db);
        atomicMin(&bestd[cv],db);
      }
    }
    __syncthreads();
    for(int e=tid;e<EEE;e+=TPW){
      int u,v; edge_uv(e,u,v);
      int cu=comp[u], cv=comp[v];
      if(cu!=cv){
        unsigned long long db=(unsigned long long)__double_as_longlong(dkey[e]);
        if(db==bestd[cu]) atomicMin(&beste[cu],e);
        if(db==bestd[cv]) atomicMin(&beste[cv],e);
      }
    }
    __syncthreads();
    // hook (mutual pair resolved toward smaller id; mutual => SAME edge since order strict)
    for(int i=tid;i<NN;i+=TPW){
      if(comp[i]==i && beste[i]!=0x7fffffff){
        int e=beste[i]; int u,v; edge_uv(e,u,v);
        int cu=comp[u], cv=comp[v];
        int other=(cu==i)?cv:cu;
        bool mutual=(beste[other]==e);
        if(!mutual || other<i){ lnk[i]=other; mstf[e]=1; flags[1]=1; }
      }
    }
    __syncthreads();
    if(flags[1]==0) break;          // no hooks => forest complete
    // ---- racy barrier-free pointer jumping (monotone-convergent) ----
    {
      volatile int* vl=lnk;
      for(int it=0;it<12;++it){
        for(int i=tid;i<NN;i+=TPW){ int a=vl[i]; int b2=vl[a]; if(a!=b2) vl[i]=b2; }
      }
      for(;;){
        if(tid==0) flags[0]=0;
        __syncthreads();
        for(int i=tid;i<NN;i+=TPW){
          int a=vl[i]; int b2=vl[a];
          if(a!=b2){ vl[i]=b2; flags[0]=1; }
        }
        __syncthreads();
        int ch=flags[0];
        __syncthreads();
        if(!ch) break;
      }
    }
    for(int i=tid;i<NN;i+=TPW) comp[i]=lnk[comp[i]];
    __syncthreads();
  }

  // ---- emit per-node adjacency mask + per-direction weights ----
  for(int i=tid;i<NN;i+=TPW){
    int r=i/WW, c=i-r*WW;
    int mask=0; float4 w; w.x=0.0f; w.y=0.0f; w.z=0.0f; w.w=0.0f;
    if(c>0    && mstf[r*(WW-1)+c-1]){ mask|=1; w.x=expf(-(float)dkey[r*(WW-1)+c-1]/sigma); }
    if(c<WW-1 && mstf[r*(WW-1)+c])  { mask|=2; w.y=expf(-(float)dkey[r*(WW-1)+c]/sigma); }
    if(r>0    && mstf[EHH+i-WW])    { mask|=4; w.z=expf(-(float)dkey[EHH+i-WW]/sigma); }
    if(r<HH-1 && mstf[EHH+i])       { mask|=8; w.w=expf(-(float)dkey[EHH+i]/sigma); }
    adjwG[(size_t)pidx*NN+i]=w;
    adjG[(size_t)pidx*NN+i]=(unsigned char)mask;
  }
}

// ---------------------------------------------------------------------------
// SINGLE-WAVE BFS: register frontier, ballot compaction, no vis array.
// Emits packed int4 (node,parent,w_bits,0) in BFS order + levelStart + depth.
__global__ __launch_bounds__(TPS) void k_bfs(
  const float4* __restrict__ adjwG, const unsigned char* __restrict__ adjG,
  int* __restrict__ sbase)
{
  __shared__ float4 adjwS[NN];       // 36864 B
  __shared__ unsigned char adjS[NN]; // 2304 B
  __shared__ int4 packedS[NN];       // 36864 B
  __shared__ int lsS[NN+2];          // 9224 B

  const int lane=threadIdx.x;
  const int pidx=blockIdx.x;
  int* sp=sbase+(size_t)pidx*SSTRIDE_W;

  {
    const float4* aw=adjwG+(size_t)pidx*NN;
    for(int t=lane;t<NN;t+=TPS) adjwS[t]=aw[t];
    const int* a4=(const int*)(adjG+(size_t)pidx*NN);
    int* s4=(int*)adjS;
    for(int t=lane;t<NN/4;t+=TPS) s4[t]=a4[t];
  }
  if(lane==0){
    packedS[0]=make_int4(0,0,__float_as_int(1.0f),0);
    lsS[0]=0; lsS[1]=1;
  }
  __syncthreads();

  int s=0, e=1, tail=1, depth=0;
  for(int l=0;;++l){
    for(int k0=s;k0<e;k0+=TPS){
      int k=k0+lane;
      int nchild=0, ci[3]; float cw[3]; int i=0;
      if(k<e){
        int4 rec=packedS[k];
        i=rec.x; int p=rec.y;
        int pm=0;
        if(p==i-1) pm=1; else if(p==i+1) pm=2;
        else if(p==i-WW) pm=4; else if(p==i+WW) pm=8;
        int cm=adjS[i]&~pm;
        float4 w4=adjwS[i];
        if(cm&1){ ci[nchild]=i-1;  cw[nchild]=w4.x; nchild++; }
        if(cm&2){ ci[nchild]=i+1;  cw[nchild]=w4.y; nchild++; }
        if(cm&4){ ci[nchild]=i-WW; cw[nchild]=w4.z; nchild++; }
        if(cm&8){ ci[nchild]=i+WW; cw[nchild]=w4.w; nchild++; }
      }
      unsigned long long m0=__ballot(nchild&1);
      unsigned long long m1=__ballot((nchild>>1)&1);
      unsigned long long lt=(1ull<<lane)-1ull;
      int pre=__popcll(m0&lt)+2*__popcll(m1&lt);
      int tot=__popcll(m0)+2*__popcll(m1);
      int base=tail+pre;
      for(int j=0;j<nchild;j++)
        packedS[base+j]=make_int4(ci[j],i,__float_as_int(cw[j]),0);
      tail+=tot;
    }
    __syncthreads();
    if(lane==0) lsS[l+2]=tail;
    if(tail==e){ depth=l; break; }
    s=e; e=tail;
  }
  __syncthreads();

  int4* g_pk=(int4*)(sp+PK_OFF);
  for(int t=lane;t<NN;t+=TPS) g_pk[t]=packedS[t];
  for(int t=lane;t<depth+2;t+=TPS) sp[L_OFF+t]=lsS[t];
  if(lane==0) sp[D_OFF]=depth;
}

// ---------------------------------------------------------------------------
// SINGLE-WAVE tree filter, forest 0 (input: softmax probs; output: AS).
__global__ __launch_bounds__(TPS) void k_filter0(
  const float* __restrict__ probf, const int* __restrict__ sbase,
  float* __restrict__ AS)
{
  __shared__ float A[(KK+1)*NN];     // 46080 B
  __shared__ int4 pkS[NN];           // 36864 B
  __shared__ int lsS[NN+2];
  const int tid=threadIdx.x;
  const int b=blockIdx.x;
  const int* sp=sbase+(size_t)b*SSTRIDE_W;
  const int D=sp[D_OFF];
  {
    const float4* pf4=(const float4*)(probf+(size_t)b*KK*NN);
    float4* A4=(float4*)A;
    for(int t=tid;t<(KK*NN)/4;t+=TPS) A4[t]=pf4[t];
    for(int t=KK*NN+tid;t<(KK+1)*NN;t+=TPS) A[t]=1.0f;
    const int4* g_pk=(const int4*)(sp+PK_OFF);
    for(int t=tid;t<NN;t+=TPS) pkS[t]=g_pk[t];
    for(int t=tid;t<D+2;t+=TPS) lsS[t]=sp[L_OFF+t];
  }
  __syncthreads();
  for(int l=D;l>=1;--l){
    int s=lsS[l], e2=lsS[l+1];
    for(int k=s+tid;k<e2;k+=TPS){
      int4 rec=pkS[k]; int i=rec.x, p=rec.y; float w=__int_as_float(rec.z);
      #pragma unroll
      for(int c=0;c<=KK;c++) atomicAdd(&A[c*NN+p], w*A[c*NN+i]);
    }
    __syncthreads();
  }
  for(int l=1;l<=D;++l){
    int s=lsS[l], e2=lsS[l+1];
    for(int k=s+tid;k<e2;k+=TPS){
      int4 rec=pkS[k]; int i=rec.x, p=rec.y; float w=__int_as_float(rec.z);
      #pragma unroll
      for(int c=0;c<=KK;c++){
        float a=A[c*NN+i];
        A[c*NN+i]=a+w*(A[c*NN+p]-w*a);
      }
    }
    __syncthreads();
  }
  {
    float4* AS4=(float4*)(AS+(size_t)b*KK*NN);
    const float4* A4=(const float4*)A;
    for(int t=tid;t<(KK*NN)/4;t+=TPS){
      int i4=t%(NN/4);
      float4 a=A4[t], d=A4[KK*(NN/4)+i4];
      float4 r; r.x=a.x/d.x; r.y=a.y/d.y; r.z=a.z/d.z; r.w=a.w/d.w;
      AS4[t]=r;
    }
  }
}

// ---------------------------------------------------------------------------
// SINGLE-WAVE tree filter, forests 1..3 (input: AS) + ROI-masked L1 partial.
__global__ __launch_bounds__(TPS) void k_filter123(
  const float* __restrict__ AS, const float* __restrict__ probf,
  const float* __restrict__ rois, const int* __restrict__ sbase,
  float* __restrict__ partials)
{
  __shared__ float A[(KK+1)*NN];
  __shared__ int4 pkS[NN];
  __shared__ int lsS[NN+2];
  const int tid=threadIdx.x;
  const int fm1=blockIdx.x/BB, b=blockIdx.x%BB;
  const int pidx=(fm1+1)*BB+b;
  const int* sp=sbase+(size_t)pidx*SSTRIDE_W;
  const int D=sp[D_OFF];
  {
    const float4* pf4=(const float4*)(AS+(size_t)b*KK*NN);
    float4* A4=(float4*)A;
    for(int t=tid;t<(KK*NN)/4;t+=TPS) A4[t]=pf4[t];
    for(int t=KK*NN+tid;t<(KK+1)*NN;t+=TPS) A[t]=1.0f;
    const int4* g_pk=(const int4*)(sp+PK_OFF);
    for(int t=tid;t<NN;t+=TPS) pkS[t]=g_pk[t];
    for(int t=tid;t<D+2;t+=TPS) lsS[t]=sp[L_OFF+t];
  }
  __syncthreads();
  for(int l=D;l>=1;--l){
    int s=lsS[l], e2=lsS[l+1];
    for(int k=s+tid;k<e2;k+=TPS){
      int4 rec=pkS[k]; int i=rec.x, p=rec.y; float w=__int_as_float(rec.z);
      #pragma unroll
      for(int c=0;c<=KK;c++) atomicAdd(&A[c*NN+p], w*A[c*NN+i]);
    }
    __syncthreads();
  }
  for(int l=1;l<=D;++l){
    int s=lsS[l], e2=lsS[l+1];
    for(int k=s+tid;k<e2;k+=TPS){
      int4 rec=pkS[k]; int i=rec.x, p=rec.y; float w=__int_as_float(rec.z);
      #pragma unroll
      for(int c=0;c<=KK;c++){
        float a=A[c*NN+i];
        A[c*NN+i]=a+w*(A[c*NN+p]-w*a);
      }
    }
    __syncthreads();
  }
  float part=0.0f;
  for(int i=tid;i<NN;i+=TPS){
    int r=i/WW, c2=i-r*WW;
    float roi=rois[(size_t)b*(192*192)+(4*r)*192+(4*c2)];
    float den=A[KK*NN+i];
    float s=0.0f;
    #pragma unroll
    for(int c=0;c<KK;c++){
      float ask=A[c*NN+i]/den;
      s+=fabsf(probf[(size_t)b*KK*NN+c*NN+i]-ask);
    }
    part+=roi*s;
  }
  #pragma unroll
  for(int s2=32;s2>0;s2>>=1) part+=__shfl_down(part,s2,64);
  if(tid==0) partials[blockIdx.x]=part;
}

// ---------------------------------------------------------------------------
__global__ __launch_bounds__(TPB) void k_final(const float* __restrict__ rois,
    const float* __restrict__ partials, const float* __restrict__ wt,
    float* __restrict__ out)
{
  __shared__ float red[TPB];
  const int tid=threadIdx.x;
  float n=0.0f;
  for(int t=tid;t<BB*NN;t+=TPB){
    int b=t/NN, i=t-b*NN; int r=i/WW, c=i-r*WW;
    n += rois[(size_t)b*(192*192)+(4*r)*192+(4*c)];
  }
  red[tid]=n; __syncthreads();
  for(int s=TPB/2;s>0;s>>=1){ if(tid<s) red[tid]+=red[tid+s]; __syncthreads(); }
  if(tid==0){
    float loss=0.0f;
    for(int j=0;j<3*BB;j++) loss+=partials[j];
    float N=red[0];
    out[0]=wt[0]*((N>0.0f)?(loss/N):loss);
  }
}

// ---------------------------------------------------------------------------
extern "C" void kernel_launch(void* const* d_in, const int* in_sizes, int n_in,
                              void* d_out, int out_size, void* d_ws, size_t ws_size,
                              hipStream_t stream) {
  (void)in_sizes; (void)n_in; (void)out_size;
  const float* preds=(const float*)d_in[0];
  const float* lowf =(const float*)d_in[1];
  const float* hf1  =(const float*)d_in[2];
  const float* hf2  =(const float*)d_in[3];
  const float* hf3  =(const float*)d_in[4];
  const float* rois =(const float*)d_in[5];
  const float* wt   =(const float*)d_in[6];
  float* out=(float*)d_out;

  char* ws=(char*)d_ws;
  float* partials=(float*)ws;                                  // 24 floats @0
  float* probf=(float*)(ws+256);                               // 294912 B
  float* AS   =(float*)(ws+256+(size_t)BB*KK*NN*4);            // 294912 B
  size_t sb_off=256+(size_t)2*BB*KK*NN*4;                      // 590080 (16B-mult)
  int*   sbase=(int*)(ws+sb_off);                              // 32*SSTRIDE_W*4 = 1475584 B
  size_t aw_off=sb_off+(size_t)32*SSTRIDE_W*4;                 // 2065664 (16B-mult)
  float4* adjwG=(float4*)(ws+aw_off);                          // 32*NN*16 = 1179648 B
  size_t aj_off=aw_off+(size_t)32*NN*16;                       // 3245312
  unsigned char* adjG=(unsigned char*)(ws+aj_off);             // 32*NN = 73728 B
  size_t pd_off=aj_off+(size_t)32*NN;                          // 3319040 (8-mult)
  double* pd=(double*)(ws+pd_off);

  int nchunk=16;
  while(nchunk>1 && pd_off+(size_t)32*nchunk*EEE*8>ws_size) nchunk>>=1;

  k_prob<<<(BB*NN+TPB-1)/TPB,TPB,0,stream>>>(preds,probf);
  k_edges<<<8+24*nchunk,TPB,0,stream>>>(lowf,hf1,hf2,hf3,pd,nchunk);
  k_boruvka<<<32,TPW,0,stream>>>(pd,nchunk,adjwG,adjG);
  k_bfs<<<32,TPS,0,stream>>>(adjwG,adjG,sbase);
  k_filter0<<<BB,TPS,0,stream>>>(probf,sbase,AS);
  k_filter123<<<3*BB,TPS,0,stream>>>(AS,probf,rois,sbase,partials);
  k_final<<<1,TPB,0,stream>>>(rois,partials,wt,out);
}

// Round 6
// 658.380 us; speedup vs baseline: 1.9030x; 1.1337x over previous
//
#include <hip/hip_runtime.h>
#include <math.h>

// ---------------------------------------------------------------------------
// TreeEnergyLoss on MI355X.
// softmax -> k_edges (parallel chunked f64 edge distances via LDS-upsampled
// embeddings) -> k_boruvka (512t: Boruvka MST under strict (dist,edge-idx)
// order == reference's stable Kruskal) -> k_bfs (1 wave ballot BFS -> per-node
// (parent, w, depth)) -> k_filter0/k_filter123: tree filters via POINTER
// DOUBLING (O(log depth) rounds instead of depth-sequential levels):
//   upward  = ascending-jump two-phase scatter (exact binary-decomposition
//             delivery of weighted subtree sums),
//   downward= affine (a,b) composition doubling (F[i]=w F[p]+(1-w^2)A[i]).
// -> ROI-masked L1 loss.
// ---------------------------------------------------------------------------

#define HH 48
#define WW 48
#define NN (HH*WW)          // 2304 nodes
#define EHH (HH*(WW-1))     // 2256 horizontal edges
#define EEE (2*EHH)         // 4512 edges
#define BB 8
#define KK 4
#define TPB 256
#define TPS 64              // single-wave BFS
#define TPW 512             // boruvka kernel
#define TPF 256             // filter kernels
#define NPL 9               // nodes per lane in filters (2304/256)
#define NE_PT ((EEE+TPB-1)/TPB)

// per-problem structure record in ws (ints): node-indexed int4 (parent,w,depth,0) | maxdepth
#define SSTRIDE_W (4*NN+8)
#define PK_OFF 0
#define D_OFF (4*NN)

struct Tap { int o00,o01,o10,o11; float w00,w01,w10,w11; };

__device__ __forceinline__ Tap mk_tap(int r,int c,int sh,int sw){
  float sy=(float)sh/48.0f, sx=(float)sw/48.0f;          // exact (pow2 ratios)
  float ys=fmaxf(((float)r+0.5f)*sy-0.5f,0.0f);
  float xs=fmaxf(((float)c+0.5f)*sx-0.5f,0.0f);
  int y0=(int)ys; if(y0>sh-1) y0=sh-1;
  int x0=(int)xs; if(x0>sw-1) x0=sw-1;
  int y1=y0+1; if(y1>sh-1) y1=sh-1;
  int x1=x0+1; if(x1>sw-1) x1=sw-1;
  float wy=ys-(float)y0, wx=xs-(float)x0;
  Tap t;
  t.o00=y0*sw+x0; t.o01=y0*sw+x1; t.o10=y1*sw+x0; t.o11=y1*sw+x1;
  t.w00=(1.0f-wy)*(1.0f-wx); t.w01=(1.0f-wy)*wx;
  t.w10=wy*(1.0f-wx);        t.w11=wy*wx;
  return t;
}

__device__ __forceinline__ float tap_val(const float* __restrict__ p, const Tap& t){
  return t.w00*p[t.o00]+t.w01*p[t.o01]+t.w10*p[t.o10]+t.w11*p[t.o11];
}

// numpy edge order: horizontal (row-major) first, then vertical.
__device__ __forceinline__ void edge_uv(int e,int& u,int& v){
  if(e<EHH){ int r=e/(WW-1); int c=e-r*(WW-1); u=r*WW+c; v=u+1; }
  else     { int t=e-EHH; u=t; v=t+WW; }
}

__device__ __forceinline__ void pick_src(int f, const float* lowf, const float* hf1,
                                         const float* hf2, const float* hf3,
                                         const float*& src, int& sh, int& C){
  if(f==0){src=lowf; sh=192; C=3;}
  else if(f==1){src=hf1; sh=24; C=512;}
  else if(f==2){src=hf2; sh=12; C=512;}
  else        {src=hf3; sh=6;  C=512;}
}

// ---------------------------------------------------------------------------
__global__ __launch_bounds__(TPB) void k_prob(const float* __restrict__ preds,
                                              float* __restrict__ probf){
  int t=blockIdx.x*TPB+threadIdx.x;
  if(t>=BB*NN) return;
  int b=t/NN, i=t-b*NN;
  const float* p=preds+(size_t)b*KK*NN+i;
  float x0=p[0],x1=p[NN],x2=p[2*NN],x3=p[3*NN];
  float mx=fmaxf(fmaxf(x0,x1),fmaxf(x2,x3));
  float e0=expf(x0-mx),e1=expf(x1-mx),e2=expf(x2-mx),e3=expf(x3-mx);
  float s=((e0+e1)+(e2+e3));
  float* q=probf+(size_t)b*KK*NN+i;
  q[0]=e0/s; q[NN]=e1/s; q[2*NN]=e2/s; q[3*NN]=e3/s;
}

// ---------------------------------------------------------------------------
// Parallel edge-distance partials.  One block = (problem, channel-chunk).
__global__ __launch_bounds__(TPB) void k_edges(
  const float* __restrict__ lowf, const float* __restrict__ hf1,
  const float* __restrict__ hf2, const float* __restrict__ hf3,
  double* __restrict__ pd, int nchunk)
{
  __shared__ float up[8*NN];   // 73728 B
  const int tid=threadIdx.x;
  int pidx, chunk;
  if(blockIdx.x<8){ pidx=blockIdx.x; chunk=0; }
  else { int t=blockIdx.x-8; pidx=8+t/nchunk; chunk=t%nchunk; }
  const int f=pidx>>3, b=pidx&7;
  const float* src; int sh,C;
  pick_src(f,lowf,hf1,hf2,hf3,src,sh,C);
  const int shw=sh*sh;
  const float* srcb=src+(size_t)b*C*shw;
  const int cpc=(f==0)?3:(512/nchunk);
  const int c_begin=chunk*cpc;
  const int c_end=(c_begin+cpc<C)?(c_begin+cpc):C;

  double acc[NE_PT];
  #pragma unroll
  for(int j=0;j<NE_PT;j++) acc[j]=0.0;

  for(int c0=c_begin;c0<c_end;c0+=8){
    const int nc=(c_end-c0<8)?(c_end-c0):8;
    __syncthreads();               // protect previous sub-stage reads
    for(int i=tid;i<NN;i+=TPB){
      Tap t=mk_tap(i/WW,i-(i/WW)*WW,sh,sh);
      const float* pl=srcb+(size_t)c0*shw;
      for(int c=0;c<nc;c++) up[c*NN+i]=tap_val(pl+(size_t)c*shw,t);
    }
    __syncthreads();
    #pragma unroll
    for(int j=0;j<NE_PT;j++){
      int e=tid+j*TPB;
      if(e<EEE){
        int u,v; edge_uv(e,u,v);
        double s=acc[j];
        for(int c=0;c<nc;c++){
          double d=(double)up[c*NN+u]-(double)up[c*NN+v];
          s=fma(d,d,s);
        }
        acc[j]=s;
      }
    }
  }
  #pragma unroll
  for(int j=0;j<NE_PT;j++){
    int e=tid+j*TPB;
    if(e<EEE) pd[((size_t)pidx*nchunk+chunk)*EEE+e]=acc[j];
  }
}

// ---------------------------------------------------------------------------
// 512-thread Boruvka per (forest,batch).
// Outputs per-node tree-adjacency mask (L,R,U,D bits) + per-direction weights.
__global__ __launch_bounds__(TPW) void k_boruvka(
  const double* __restrict__ pd, int nchunk,
  float4* __restrict__ adjwG, unsigned char* __restrict__ adjG)
{
  __shared__ double dkey[EEE];                  // 36096 B
  __shared__ unsigned long long bestd[NN];      // 18432 B
  __shared__ int comp[NN];
  __shared__ int lnk[NN];
  __shared__ int beste[NN];
  __shared__ unsigned char mstf[EEE];
  __shared__ int flags[2];

  const int tid=threadIdx.x;
  const int pidx=blockIdx.x;
  const int f=pidx>>3;
  const float sigma=(f==0)?0.02f:1.0f;

  // ---- gather edge distances: fixed chunk order (deterministic) ----
  const int nck=(f==0)?1:nchunk;
  for(int e=tid;e<EEE;e+=TPW){
    const double* p=pd+((size_t)pidx*nchunk)*EEE+e;
    double s=0.0;
    for(int k=0;k<nck;k++) s+=p[(size_t)k*EEE];
    dkey[e]=s;
  }
  for(int i=tid;i<NN;i+=TPW) comp[i]=i;
  for(int e=tid;e<EEE;e+=TPW) mstf[e]=0;
  __syncthreads();

  // ---- Boruvka: unique MST under strict (dist_bits, edge_index) order ----
  for(int round=0;round<24;++round){
    for(int i=tid;i<NN;i+=TPW){ bestd[i]=~0ull; beste[i]=0x7fffffff; lnk[i]=i; }
    if(tid==0) flags[1]=0;
    __syncthreads();
    for(int e=tid;e<EEE;e+=TPW){
      int u,v; edge_uv(e,u,v);
      int cu=comp[u], cv=comp[v];
      if(cu!=cv){
        unsigned long long db=(unsigned long long)__double_as_longlong(dkey[e]);
        atomicMin(&bestd[cu],db);
        atomicMin(&bestd[cv],db);
      }
    }
    __syncthreads();
    for(int e=tid;e<EEE;e+=TPW){
      int u,v; edge_uv(e,u,v);
      int cu=comp[u], cv=comp[v];
      if(cu!=cv){
        unsigned long long db=(unsigned long long)__double_as_longlong(dkey[e]);
        if(db==bestd[cu]) atomicMin(&beste[cu],e);
        if(db==bestd[cv]) atomicMin(&beste[cv],e);
      }
    }
    __syncthreads();
    // hook (mutual pair resolved toward smaller id; mutual => SAME edge since order strict)
    for(int i=tid;i<NN;i+=TPW){
      if(comp[i]==i && beste[i]!=0x7fffffff){
        int e=beste[i]; int u,v; edge_uv(e,u,v);
        int cu=comp[u], cv=comp[v];
        int other=(cu==i)?cv:cu;
        bool mutual=(beste[other]==e);
        if(!mutual || other<i){ lnk[i]=other; mstf[e]=1; flags[1]=1; }
      }
    }
    __syncthreads();
    if(flags[1]==0) break;          // no hooks => forest complete
    // ---- racy barrier-free pointer jumping (monotone-convergent) ----
    {
      volatile int* vl=lnk;
      for(int it=0;it<12;++it){
        for(int i=tid;i<NN;i+=TPW){ int a=vl[i]; int b2=vl[a]; if(a!=b2) vl[i]=b2; }
      }
      for(;;){
        if(tid==0) flags[0]=0;
        __syncthreads();
        for(int i=tid;i<NN;i+=TPW){
          int a=vl[i]; int b2=vl[a];
          if(a!=b2){ vl[i]=b2; flags[0]=1; }
        }
        __syncthreads();
        int ch=flags[0];
        __syncthreads();
        if(!ch) break;
      }
    }
    for(int i=tid;i<NN;i+=TPW) comp[i]=lnk[comp[i]];
    __syncthreads();
  }

  // ---- emit per-node adjacency mask + per-direction weights ----
  for(int i=tid;i<NN;i+=TPW){
    int r=i/WW, c=i-r*WW;
    int mask=0; float4 w; w.x=0.0f; w.y=0.0f; w.z=0.0f; w.w=0.0f;
    if(c>0    && mstf[r*(WW-1)+c-1]){ mask|=1; w.x=expf(-(float)dkey[r*(WW-1)+c-1]/sigma); }
    if(c<WW-1 && mstf[r*(WW-1)+c])  { mask|=2; w.y=expf(-(float)dkey[r*(WW-1)+c]/sigma); }
    if(r>0    && mstf[EHH+i-WW])    { mask|=4; w.z=expf(-(float)dkey[EHH+i-WW]/sigma); }
    if(r<HH-1 && mstf[EHH+i])       { mask|=8; w.w=expf(-(float)dkey[EHH+i]/sigma); }
    adjwG[(size_t)pidx*NN+i]=w;
    adjG[(size_t)pidx*NN+i]=(unsigned char)mask;
  }
}

// ---------------------------------------------------------------------------
// SINGLE-WAVE BFS: register frontier, ballot compaction, no vis array.
// Emits node-indexed int4 (parent, w_bits, depth, 0) + maxdepth.
__global__ __launch_bounds__(TPS) void k_bfs(
  const float4* __restrict__ adjwG, const unsigned char* __restrict__ adjG,
  int* __restrict__ sbase)
{
  __shared__ float4 adjwS[NN];       // 36864 B
  __shared__ unsigned char adjS[NN]; // 2304 B
  __shared__ int4 packedS[NN];       // 36864 B
  __shared__ int depthS[NN];         // 9216 B
  __shared__ int lsS[NN+2];          // 9224 B

  const int lane=threadIdx.x;
  const int pidx=blockIdx.x;
  int* sp=sbase+(size_t)pidx*SSTRIDE_W;

  {
    const float4* aw=adjwG+(size_t)pidx*NN;
    for(int t=lane;t<NN;t+=TPS) adjwS[t]=aw[t];
    const int* a4=(const int*)(adjG+(size_t)pidx*NN);
    int* s4=(int*)adjS;
    for(int t=lane;t<NN/4;t+=TPS) s4[t]=a4[t];
  }
  if(lane==0){
    packedS[0]=make_int4(0,0,__float_as_int(0.0f),0);   // root: parent=0, w=0
    depthS[0]=0;
    lsS[0]=0; lsS[1]=1;
  }
  __syncthreads();

  int s=0, e=1, tail=1, depth=0;
  for(int l=0;;++l){
    for(int k0=s;k0<e;k0+=TPS){
      int k=k0+lane;
      int nchild=0, ci[3]; float cw[3]; int i=0;
      if(k<e){
        int4 rec=packedS[k];
        i=rec.x; int p=rec.y;
        int pm=0;
        if(p==i-1) pm=1; else if(p==i+1) pm=2;
        else if(p==i-WW) pm=4; else if(p==i+WW) pm=8;
        if(k==0) pm=0;
        int cm=adjS[i]&~pm;
        float4 w4=adjwS[i];
        if(cm&1){ ci[nchild]=i-1;  cw[nchild]=w4.x; nchild++; }
        if(cm&2){ ci[nchild]=i+1;  cw[nchild]=w4.y; nchild++; }
        if(cm&4){ ci[nchild]=i-WW; cw[nchild]=w4.z; nchild++; }
        if(cm&8){ ci[nchild]=i+WW; cw[nchild]=w4.w; nchild++; }
      }
      unsigned long long m0=__ballot(nchild&1);
      unsigned long long m1=__ballot((nchild>>1)&1);
      unsigned long long lt=(1ull<<lane)-1ull;
      int pre=__popcll(m0&lt)+2*__popcll(m1&lt);
      int tot=__popcll(m0)+2*__popcll(m1);
      int base=tail+pre;
      for(int j=0;j<nchild;j++){
        packedS[base+j]=make_int4(ci[j],i,__float_as_int(cw[j]),0);
        depthS[ci[j]]=l+1;
      }
      tail+=tot;
    }
    __syncthreads();
    if(lane==0) lsS[l+2]=tail;
    if(tail==e){ depth=l; break; }
    s=e; e=tail;
  }
  __syncthreads();

  int4* g_pk=(int4*)(sp+PK_OFF);
  for(int k=lane;k<NN;k+=TPS){
    int4 rec=packedS[k];
    g_pk[rec.x]=make_int4(rec.y, rec.z, depthS[rec.x], 0);
  }
  if(lane==0) sp[D_OFF]=depth;
}

// ---------------------------------------------------------------------------
// Pointer-doubling tree filter core (upward scatter + downward affine compose).
// Each of TPF=256 lanes owns NPL=9 nodes i = tid + j*256.  All per-node state
// in registers (loops fully unrolled -> static indexing).
// ---------------------------------------------------------------------------
#define FILTER_CORE(X_LOAD)                                                     \
  const int tid=threadIdx.x;                                                    \
  const int maxD=sp[D_OFF];                                                     \
  int T=1; while((1<<T)<=maxD) T++;                                             \
  int parR[NPL]; float wR[NPL]; int depR[NPL];                                  \
  int ancR[NPL]; float prodR[NPL];                                              \
  const int4* g_pk=(const int4*)(sp+PK_OFF);                                    \
  _Pragma("unroll")                                                             \
  for(int j=0;j<NPL;j++){                                                       \
    int i=tid+j*TPF;                                                            \
    int4 rec=g_pk[i];                                                           \
    parR[j]=rec.x; wR[j]=__int_as_float(rec.y); depR[j]=rec.z;                  \
    ancR[j]=parR[j]; prodR[j]=wR[j];                                            \
    ancL[0][i]=parR[j]; prodL[0][i]=wR[j];                                      \
  }                                                                             \
  { X_LOAD }                                                                    \
  __syncthreads();                                                              \
  /* ---- upward: ascending-jump two-phase scatter ---- */                      \
  int ping=0;                                                                   \
  for(int t=0;t<T;t++){                                                         \
    float s0[NPL],s1[NPL],s2[NPL],s3[NPL],s4[NPL];                              \
    _Pragma("unroll")                                                           \
    for(int j=0;j<NPL;j++){                                                     \
      int i=tid+j*TPF;                                                          \
      s0[j]=S[i]; s1[j]=S[NN+i]; s2[j]=S[2*NN+i];                               \
      s3[j]=S[3*NN+i]; s4[j]=S[4*NN+i];                                         \
    }                                                                           \
    __syncthreads();                                                            \
    _Pragma("unroll")                                                           \
    for(int j=0;j<NPL;j++){                                                     \
      int i=tid+j*TPF;                                                          \
      int a=ancR[j];                                                            \
      if(depR[j]>=(1<<t)){                                                      \
        float pw=prodR[j];                                                      \
        atomicAdd(&S[a],      pw*s0[j]);                                        \
        atomicAdd(&S[NN+a],   pw*s1[j]);                                        \
        atomicAdd(&S[2*NN+a], pw*s2[j]);                                        \
        atomicAdd(&S[3*NN+a], pw*s3[j]);                                        \
        atomicAdd(&S[4*NN+a], pw*s4[j]);                                        \
      }                                                                         \
      int a2=ancL[ping][a]; float p2=prodL[ping][a];                            \
      ancR[j]=a2; prodR[j]*=p2;                                                 \
      ancL[1-ping][i]=a2; prodL[1-ping][i]=prodR[j];                            \
    }                                                                           \
    __syncthreads();                                                            \
    ping^=1;                                                                    \
  }                                                                             \
  /* ---- downward: affine (a,b) composition doubling ---- */                   \
  float b0[NPL],b1[NPL],b2[NPL],b3[NPL],b4[NPL]; float aR[NPL];                 \
  _Pragma("unroll")                                                             \
  for(int j=0;j<NPL;j++){                                                       \
    int i=tid+j*TPF;                                                            \
    float w=wR[j]; float fq=1.0f-w*w;                                           \
    b0[j]=fq*S[i]; b1[j]=fq*S[NN+i]; b2[j]=fq*S[2*NN+i];                        \
    b3[j]=fq*S[3*NN+i]; b4[j]=fq*S[4*NN+i];                                     \
    aR[j]=w; ancR[j]=parR[j];                                                   \
    ancL[0][i]=parR[j]; prodL[0][i]=w;                                          \
  }                                                                             \
  __syncthreads();                                                              \
  _Pragma("unroll")                                                             \
  for(int j=0;j<NPL;j++){                                                       \
    int i=tid+j*TPF;                                                            \
    S[i]=b0[j]; S[NN+i]=b1[j]; S[2*NN+i]=b2[j];                                 \
    S[3*NN+i]=b3[j]; S[4*NN+i]=b4[j];                                           \
  }                                                                             \
  __syncthreads();                                                              \
  ping=0;                                                                       \
  for(int t=0;t<T;t++){                                                         \
    float* bfP = ping? bFB : S;                                                 \
    float* bfQ = ping? S : bFB;                                                 \
    _Pragma("unroll")                                                           \
    for(int j=0;j<NPL;j++){                                                     \
      int i=tid+j*TPF;                                                          \
      int a=ancR[j];                                                            \
      float aa=prodL[ping][a];                                                  \
      int   a2=ancL[ping][a];                                                   \
      float t0=bfP[a],t1=bfP[NN+a],t2=bfP[2*NN+a],t3=bfP[3*NN+a],t4=bfP[4*NN+a];\
      b0[j]=fmaf(aR[j],t0,b0[j]); b1[j]=fmaf(aR[j],t1,b1[j]);                   \
      b2[j]=fmaf(aR[j],t2,b2[j]); b3[j]=fmaf(aR[j],t3,b3[j]);                   \
      b4[j]=fmaf(aR[j],t4,b4[j]);                                               \
      aR[j]*=aa; ancR[j]=a2;                                                    \
      bfQ[i]=b0[j]; bfQ[NN+i]=b1[j]; bfQ[2*NN+i]=b2[j];                         \
      bfQ[3*NN+i]=b3[j]; bfQ[4*NN+i]=b4[j];                                     \
      ancL[1-ping][i]=a2; prodL[1-ping][i]=aR[j];                               \
    }                                                                           \
    __syncthreads();                                                            \
    ping^=1;                                                                    \
  }                                                                             \
  float* bfP = ping? bFB : S;                                                   \
  float r0=bfP[0],r1=bfP[NN],r2=bfP[2*NN],r3=bfP[3*NN],r4=bfP[4*NN];

// ---------------------------------------------------------------------------
__global__ __launch_bounds__(TPF) void k_filter0(
  const float* __restrict__ probf, const int* __restrict__ sbase,
  float* __restrict__ AS)
{
  __shared__ float S[5*NN];      // 46080 B (x -> A_up -> bF ping)
  __shared__ float bFB[5*NN];    // 46080 B (bF pong)
  __shared__ int   ancL[2][NN];  // 18432 B
  __shared__ float prodL[2][NN]; // 18432 B
  const int b=blockIdx.x;
  const int* sp=sbase+(size_t)b*SSTRIDE_W;
  FILTER_CORE(
    const float4* pf4=(const float4*)(probf+(size_t)b*KK*NN);
    float4* S4=(float4*)S;
    for(int t2=tid;t2<(KK*NN)/4;t2+=TPF) S4[t2]=pf4[t2];
    for(int t2=KK*NN+tid;t2<5*NN;t2+=TPF) S[t2]=1.0f;
  )
  #pragma unroll
  for(int j=0;j<NPL;j++){
    int i=tid+j*TPF;
    float F0=fmaf(aR[j],r0,b0[j]);
    float F1=fmaf(aR[j],r1,b1[j]);
    float F2=fmaf(aR[j],r2,b2[j]);
    float F3=fmaf(aR[j],r3,b3[j]);
    float F4=fmaf(aR[j],r4,b4[j]);
    float inv=1.0f/F4;
    float* o=AS+(size_t)b*KK*NN;
    o[i]=F0*inv; o[NN+i]=F1*inv; o[2*NN+i]=F2*inv; o[3*NN+i]=F3*inv;
  }
}

// ---------------------------------------------------------------------------
__global__ __launch_bounds__(TPF) void k_filter123(
  const float* __restrict__ AS, const float* __restrict__ probf,
  const float* __restrict__ rois, const int* __restrict__ sbase,
  float* __restrict__ partials)
{
  __shared__ float S[5*NN];
  __shared__ float bFB[5*NN];
  __shared__ int   ancL[2][NN];
  __shared__ float prodL[2][NN];
  __shared__ float red[TPF];
  const int fm1=blockIdx.x/BB, b=blockIdx.x%BB;
  const int pidx=(fm1+1)*BB+b;
  const int* sp=sbase+(size_t)pidx*SSTRIDE_W;
  FILTER_CORE(
    const float4* pf4=(const float4*)(AS+(size_t)b*KK*NN);
    float4* S4=(float4*)S;
    for(int t2=tid;t2<(KK*NN)/4;t2+=TPF) S4[t2]=pf4[t2];
    for(int t2=KK*NN+tid;t2<5*NN;t2+=TPF) S[t2]=1.0f;
  )
  float part=0.0f;
  #pragma unroll
  for(int j=0;j<NPL;j++){
    int i=tid+j*TPF;
    int r=i/WW, c2=i-r*WW;
    float roi=rois[(size_t)b*(192*192)+(4*r)*192+(4*c2)];
    float F4=fmaf(aR[j],r4,b4[j]);
    float inv=1.0f/F4;
    const float* pb=probf+(size_t)b*KK*NN;
    float s=fabsf(pb[i]       - fmaf(aR[j],r0,b0[j])*inv)
          + fabsf(pb[NN+i]    - fmaf(aR[j],r1,b1[j])*inv)
          + fabsf(pb[2*NN+i]  - fmaf(aR[j],r2,b2[j])*inv)
          + fabsf(pb[3*NN+i]  - fmaf(aR[j],r3,b3[j])*inv);
    part+=roi*s;
  }
  red[tid]=part; __syncthreads();
  for(int s2=TPF/2;s2>0;s2>>=1){ if(tid<s2) red[tid]+=red[tid+s2]; __syncthreads(); }
  if(tid==0) partials[blockIdx.x]=red[0];
}

// ---------------------------------------------------------------------------
__global__ __launch_bounds__(TPB) void k_final(const float* __restrict__ rois,
    const float* __restrict__ partials, const float* __restrict__ wt,
    float* __restrict__ out)
{
  __shared__ float red[TPB];
  const int tid=threadIdx.x;
  float n=0.0f;
  for(int t=tid;t<BB*NN;t+=TPB){
    int b=t/NN, i=t-b*NN; int r=i/WW, c=i-r*WW;
    n += rois[(size_t)b*(192*192)+(4*r)*192+(4*c)];
  }
  red[tid]=n; __syncthreads();
  for(int s=TPB/2;s>0;s>>=1){ if(tid<s) red[tid]+=red[tid+s]; __syncthreads(); }
  if(tid==0){
    float loss=0.0f;
    for(int j=0;j<3*BB;j++) loss+=partials[j];
    float N=red[0];
    out[0]=wt[0]*((N>0.0f)?(loss/N):loss);
  }
}

// ---------------------------------------------------------------------------
extern "C" void kernel_launch(void* const* d_in, const int* in_sizes, int n_in,
                              void* d_out, int out_size, void* d_ws, size_t ws_size,
                              hipStream_t stream) {
  (void)in_sizes; (void)n_in; (void)out_size;
  const float* preds=(const float*)d_in[0];
  const float* lowf =(const float*)d_in[1];
  const float* hf1  =(const float*)d_in[2];
  const float* hf2  =(const float*)d_in[3];
  const float* hf3  =(const float*)d_in[4];
  const float* rois =(const float*)d_in[5];
  const float* wt   =(const float*)d_in[6];
  float* out=(float*)d_out;

  char* ws=(char*)d_ws;
  float* partials=(float*)ws;                                  // 24 floats @0
  float* probf=(float*)(ws+256);                               // 294912 B
  float* AS   =(float*)(ws+256+(size_t)BB*KK*NN*4);            // 294912 B
  size_t sb_off=256+(size_t)2*BB*KK*NN*4;                      // 590080
  int*   sbase=(int*)(ws+sb_off);                              // 32*SSTRIDE_W*4 = 1180672 B
  size_t aw_off=sb_off+(size_t)32*SSTRIDE_W*4;                 // 1770752
  float4* adjwG=(float4*)(ws+aw_off);                          // 32*NN*16 = 1179648 B
  size_t aj_off=aw_off+(size_t)32*NN*16;                       // 2950400
  unsigned char* adjG=(unsigned char*)(ws+aj_off);             // 32*NN = 73728 B
  size_t pd_off=aj_off+(size_t)32*NN;                          // 3024128 (8-mult)
  double* pd=(double*)(ws+pd_off);

  int nchunk=16;
  while(nchunk>1 && pd_off+(size_t)32*nchunk*EEE*8>ws_size) nchunk>>=1;

  k_prob<<<(BB*NN+TPB-1)/TPB,TPB,0,stream>>>(preds,probf);
  k_edges<<<8+24*nchunk,TPB,0,stream>>>(lowf,hf1,hf2,hf3,pd,nchunk);
  k_boruvka<<<32,TPW,0,stream>>>(pd,nchunk,adjwG,adjG);
  k_bfs<<<32,TPS,0,stream>>>(adjwG,adjG,sbase);
  k_filter0<<<BB,TPF,0,stream>>>(probf,sbase,AS);
  k_filter123<<<3*BB,TPF,0,stream>>>(AS,probf,rois,sbase,partials);
  k_final<<<1,TPB,0,stream>>>(rois,partials,wt,out);
}

// Round 7
// 558.494 us; speedup vs baseline: 2.2433x; 1.1788x over previous
//
#include <hip/hip_runtime.h>
#include <math.h>

// ---------------------------------------------------------------------------
// TreeEnergyLoss on MI355X.
// softmax -> k_edges (parallel chunked f64 edge distances via LDS-upsampled
// embeddings) -> k_boruvka (512t: Boruvka MST under strict (dist,edge-idx)
// order == reference's stable Kruskal) -> k_root (512t: Euler-tour rooting via
// Wyllie list-ranking, O(log n) rounds -> per-node (parent,w,depth)+maxdepth)
// -> k_filter0/k_filter123: tree filters via pointer doubling (O(log depth)):
//   upward  = ascending-jump two-phase scatter,
//   downward= affine (a,b) composition doubling (F[i]=w F[p]+(1-w^2)A[i]).
// -> ROI-masked L1 loss.
// ---------------------------------------------------------------------------

#define HH 48
#define WW 48
#define NN (HH*WW)          // 2304 nodes
#define EHH (HH*(WW-1))     // 2256 horizontal edges
#define EEE (2*EHH)         // 4512 edges
#define BB 8
#define KK 4
#define TPB 256
#define TPW 512             // boruvka kernel
#define TPR 512             // rooting kernel
#define TPF 256             // filter kernels
#define NPL 9               // nodes per lane in filters (2304/256)
#define NE_PT ((EEE+TPB-1)/TPB)
#define ESLOT (4*NN)        // 9216 directed-edge slots
#define LVE (2*(NN-1))      // 4606 valid directed edges
#define SENTN 0xFFFFu

// per-problem structure record in ws (ints): node-indexed int4 (parent,w,depth,0) | maxdepth
#define SSTRIDE_W (4*NN+8)
#define PK_OFF 0
#define D_OFF (4*NN)

struct Tap { int o00,o01,o10,o11; float w00,w01,w10,w11; };

__device__ __forceinline__ Tap mk_tap(int r,int c,int sh,int sw){
  float sy=(float)sh/48.0f, sx=(float)sw/48.0f;          // exact (pow2 ratios)
  float ys=fmaxf(((float)r+0.5f)*sy-0.5f,0.0f);
  float xs=fmaxf(((float)c+0.5f)*sx-0.5f,0.0f);
  int y0=(int)ys; if(y0>sh-1) y0=sh-1;
  int x0=(int)xs; if(x0>sw-1) x0=sw-1;
  int y1=y0+1; if(y1>sh-1) y1=sh-1;
  int x1=x0+1; if(x1>sw-1) x1=sw-1;
  float wy=ys-(float)y0, wx=xs-(float)x0;
  Tap t;
  t.o00=y0*sw+x0; t.o01=y0*sw+x1; t.o10=y1*sw+x0; t.o11=y1*sw+x1;
  t.w00=(1.0f-wy)*(1.0f-wx); t.w01=(1.0f-wy)*wx;
  t.w10=wy*(1.0f-wx);        t.w11=wy*wx;
  return t;
}

__device__ __forceinline__ float tap_val(const float* __restrict__ p, const Tap& t){
  return t.w00*p[t.o00]+t.w01*p[t.o01]+t.w10*p[t.o10]+t.w11*p[t.o11];
}

// numpy edge order: horizontal (row-major) first, then vertical.
__device__ __forceinline__ void edge_uv(int e,int& u,int& v){
  if(e<EHH){ int r=e/(WW-1); int c=e-r*(WW-1); u=r*WW+c; v=u+1; }
  else     { int t=e-EHH; u=t; v=t+WW; }
}

__device__ __forceinline__ void pick_src(int f, const float* lowf, const float* hf1,
                                         const float* hf2, const float* hf3,
                                         const float*& src, int& sh, int& C){
  if(f==0){src=lowf; sh=192; C=3;}
  else if(f==1){src=hf1; sh=24; C=512;}
  else if(f==2){src=hf2; sh=12; C=512;}
  else        {src=hf3; sh=6;  C=512;}
}

// ---------------------------------------------------------------------------
__global__ __launch_bounds__(TPB) void k_prob(const float* __restrict__ preds,
                                              float* __restrict__ probf){
  int t=blockIdx.x*TPB+threadIdx.x;
  if(t>=BB*NN) return;
  int b=t/NN, i=t-b*NN;
  const float* p=preds+(size_t)b*KK*NN+i;
  float x0=p[0],x1=p[NN],x2=p[2*NN],x3=p[3*NN];
  float mx=fmaxf(fmaxf(x0,x1),fmaxf(x2,x3));
  float e0=expf(x0-mx),e1=expf(x1-mx),e2=expf(x2-mx),e3=expf(x3-mx);
  float s=((e0+e1)+(e2+e3));
  float* q=probf+(size_t)b*KK*NN+i;
  q[0]=e0/s; q[NN]=e1/s; q[2*NN]=e2/s; q[3*NN]=e3/s;
}

// ---------------------------------------------------------------------------
// Parallel edge-distance partials.  One block = (problem, channel-chunk).
__global__ __launch_bounds__(TPB) void k_edges(
  const float* __restrict__ lowf, const float* __restrict__ hf1,
  const float* __restrict__ hf2, const float* __restrict__ hf3,
  double* __restrict__ pd, int nchunk)
{
  __shared__ float up[8*NN];   // 73728 B
  const int tid=threadIdx.x;
  int pidx, chunk;
  if(blockIdx.x<8){ pidx=blockIdx.x; chunk=0; }
  else { int t=blockIdx.x-8; pidx=8+t/nchunk; chunk=t%nchunk; }
  const int f=pidx>>3, b=pidx&7;
  const float* src; int sh,C;
  pick_src(f,lowf,hf1,hf2,hf3,src,sh,C);
  const int shw=sh*sh;
  const float* srcb=src+(size_t)b*C*shw;
  const int cpc=(f==0)?3:(512/nchunk);
  const int c_begin=chunk*cpc;
  const int c_end=(c_begin+cpc<C)?(c_begin+cpc):C;

  double acc[NE_PT];
  #pragma unroll
  for(int j=0;j<NE_PT;j++) acc[j]=0.0;

  for(int c0=c_begin;c0<c_end;c0+=8){
    const int nc=(c_end-c0<8)?(c_end-c0):8;
    __syncthreads();               // protect previous sub-stage reads
    for(int i=tid;i<NN;i+=TPB){
      Tap t=mk_tap(i/WW,i-(i/WW)*WW,sh,sh);
      const float* pl=srcb+(size_t)c0*shw;
      for(int c=0;c<nc;c++) up[c*NN+i]=tap_val(pl+(size_t)c*shw,t);
    }
    __syncthreads();
    #pragma unroll
    for(int j=0;j<NE_PT;j++){
      int e=tid+j*TPB;
      if(e<EEE){
        int u,v; edge_uv(e,u,v);
        double s=acc[j];
        for(int c=0;c<nc;c++){
          double d=(double)up[c*NN+u]-(double)up[c*NN+v];
          s=fma(d,d,s);
        }
        acc[j]=s;
      }
    }
  }
  #pragma unroll
  for(int j=0;j<NE_PT;j++){
    int e=tid+j*TPB;
    if(e<EEE) pd[((size_t)pidx*nchunk+chunk)*EEE+e]=acc[j];
  }
}

// ---------------------------------------------------------------------------
// 512-thread Boruvka per (forest,batch).
// Outputs per-node tree-adjacency mask (L,R,U,D bits) + per-direction weights.
__global__ __launch_bounds__(TPW) void k_boruvka(
  const double* __restrict__ pd, int nchunk,
  float4* __restrict__ adjwG, unsigned char* __restrict__ adjG)
{
  __shared__ double dkey[EEE];                  // 36096 B
  __shared__ unsigned long long bestd[NN];      // 18432 B
  __shared__ int comp[NN];
  __shared__ int lnk[NN];
  __shared__ int beste[NN];
  __shared__ unsigned char mstf[EEE];
  __shared__ int flags[2];

  const int tid=threadIdx.x;
  const int pidx=blockIdx.x;
  const int f=pidx>>3;
  const float sigma=(f==0)?0.02f:1.0f;

  // ---- gather edge distances: fixed chunk order (deterministic) ----
  const int nck=(f==0)?1:nchunk;
  for(int e=tid;e<EEE;e+=TPW){
    const double* p=pd+((size_t)pidx*nchunk)*EEE+e;
    double s=0.0;
    for(int k=0;k<nck;k++) s+=p[(size_t)k*EEE];
    dkey[e]=s;
  }
  for(int i=tid;i<NN;i+=TPW) comp[i]=i;
  for(int e=tid;e<EEE;e+=TPW) mstf[e]=0;
  __syncthreads();

  // ---- Boruvka: unique MST under strict (dist_bits, edge_index) order ----
  for(int round=0;round<24;++round){
    for(int i=tid;i<NN;i+=TPW){ bestd[i]=~0ull; beste[i]=0x7fffffff; lnk[i]=i; }
    if(tid==0) flags[1]=0;
    __syncthreads();
    for(int e=tid;e<EEE;e+=TPW){
      int u,v; edge_uv(e,u,v);
      int cu=comp[u], cv=comp[v];
      if(cu!=cv){
        unsigned long long db=(unsigned long long)__double_as_longlong(dkey[e]);
        atomicMin(&bestd[cu],db);
        atomicMin(&bestd[cv],db);
      }
    }
    __syncthreads();
    for(int e=tid;e<EEE;e+=TPW){
      int u,v; edge_uv(e,u,v);
      int cu=comp[u], cv=comp[v];
      if(cu!=cv){
        unsigned long long db=(unsigned long long)__double_as_longlong(dkey[e]);
        if(db==bestd[cu]) atomicMin(&beste[cu],e);
        if(db==bestd[cv]) atomicMin(&beste[cv],e);
      }
    }
    __syncthreads();
    // hook (mutual pair resolved toward smaller id; mutual => SAME edge since order strict)
    for(int i=tid;i<NN;i+=TPW){
      if(comp[i]==i && beste[i]!=0x7fffffff){
        int e=beste[i]; int u,v; edge_uv(e,u,v);
        int cu=comp[u], cv=comp[v];
        int other=(cu==i)?cv:cu;
        bool mutual=(beste[other]==e);
        if(!mutual || other<i){ lnk[i]=other; mstf[e]=1; flags[1]=1; }
      }
    }
    __syncthreads();
    if(flags[1]==0) break;          // no hooks => forest complete
    // ---- racy barrier-free pointer jumping (monotone-convergent) ----
    {
      volatile int* vl=lnk;
      for(int it=0;it<12;++it){
        for(int i=tid;i<NN;i+=TPW){ int a=vl[i]; int b2=vl[a]; if(a!=b2) vl[i]=b2; }
      }
      for(;;){
        if(tid==0) flags[0]=0;
        __syncthreads();
        for(int i=tid;i<NN;i+=TPW){
          int a=vl[i]; int b2=vl[a];
          if(a!=b2){ vl[i]=b2; flags[0]=1; }
        }
        __syncthreads();
        int ch=flags[0];
        __syncthreads();
        if(!ch) break;
      }
    }
    for(int i=tid;i<NN;i+=TPW) comp[i]=lnk[comp[i]];
    __syncthreads();
  }

  // ---- emit per-node adjacency mask + per-direction weights ----
  for(int i=tid;i<NN;i+=TPW){
    int r=i/WW, c=i-r*WW;
    int mask=0; float4 w; w.x=0.0f; w.y=0.0f; w.z=0.0f; w.w=0.0f;
    if(c>0    && mstf[r*(WW-1)+c-1]){ mask|=1; w.x=expf(-(float)dkey[r*(WW-1)+c-1]/sigma); }
    if(c<WW-1 && mstf[r*(WW-1)+c])  { mask|=2; w.y=expf(-(float)dkey[r*(WW-1)+c]/sigma); }
    if(r>0    && mstf[EHH+i-WW])    { mask|=4; w.z=expf(-(float)dkey[EHH+i-WW]/sigma); }
    if(r<HH-1 && mstf[EHH+i])       { mask|=8; w.w=expf(-(float)dkey[EHH+i]/sigma); }
    adjwG[(size_t)pidx*NN+i]=w;
    adjG[(size_t)pidx*NN+i]=(unsigned char)mask;
  }
}

// ---------------------------------------------------------------------------
// 512-thread Euler-tour rooting via Wyllie list-ranking.
// Directed-edge slot e = node*4 + dir (dir: 0=L,1=R,2=U,3=D; rev = dir^1).
// succ(u->v) = v -> first valid dir after rev(dir) cyclically (tree Euler tour).
// Ranks give tour positions; edge is DOWN iff pos < pos(reverse edge);
// depth = inclusive scan of (+1 down / -1 up) over positions.
// Emits node-indexed int4 (parent, w_bits, depth, 0) + maxdepth.
__global__ __launch_bounds__(TPR) void k_root(
  const float4* __restrict__ adjwG, const unsigned char* __restrict__ adjG,
  int* __restrict__ sbase)
{
  __shared__ unsigned int eA[ESLOT];   // 36864 B  (ping: (nxt<<16)|dist)
  __shared__ unsigned int eB[ESLOT];   // 36864 B  (pong; later pos[])
  __shared__ float4 adjwS[NN];         // 36864 B
  __shared__ unsigned char adjS[NN];   // 2304 B
  __shared__ int chunkS[TPR];          // 2048 B
  __shared__ int maxdS;

  const int tid=threadIdx.x;
  const int pidx=blockIdx.x;
  {
    const float4* aw=adjwG+(size_t)pidx*NN;
    for(int t=tid;t<NN;t+=TPR) adjwS[t]=aw[t];
    const int* a4=(const int*)(adjG+(size_t)pidx*NN);
    int* s4=(int*)adjS;
    for(int t=tid;t<NN/4;t+=TPR) s4[t]=a4[t];
  }
  if(tid==0) maxdS=0;
  __syncthreads();

  // root's first valid direction -> tour start edge e0
  const int m0=adjS[0];
  const int d0=(m0&1)?0:((m0&2)?1:((m0&4)?2:3));
  const int e0=d0;   // node 0 * 4 + d0

  // ---- build successor list, init dist=1 ----
  for(int t=tid;t<ESLOT;t+=TPR){
    int u=t>>2, d=t&3;
    unsigned int pk=0;                       // dist==0 marks invalid slot
    if(adjS[u]&(1<<d)){
      int v=(d==0)?u-1:(d==1)?u+1:(d==2)?u-WW:u+WW;
      int rd=d^1;
      int mv=adjS[v];
      int nd=rd;
      #pragma unroll
      for(int k2=4;k2>=1;k2--){ int dd=(rd+k2)&3; if(mv&(1<<dd)) nd=dd; }
      int ne=(v<<2)|nd;
      unsigned int nxt=(ne==e0)?SENTN:(unsigned int)ne;
      pk=(nxt<<16)|1u;
    }
    eA[t]=pk;
  }
  __syncthreads();

  // ---- Wyllie doubling: 13 rounds (2^13 >= 4606) ----
  unsigned int* P=eA; unsigned int* Q=eB;
  for(int r2=0;r2<13;r2++){
    for(int t=tid;t<ESLOT;t+=TPR){
      unsigned int pk=P[t];
      unsigned int dist=pk&0xFFFFu, nxt=pk>>16;
      if(dist && nxt!=SENTN){
        unsigned int pk2=P[nxt];
        dist+=pk2&0xFFFFu;
        nxt=pk2>>16;
        pk=(nxt<<16)|dist;
      }
      Q[t]=pk;
    }
    __syncthreads();
    unsigned int* tmp=P; P=Q; Q=tmp;
  }
  // pos = LVE - dist  (e0 -> 0, last edge -> LVE-1); invalid -> ~0
  for(int t=tid;t<ESLOT;t+=TPR){
    unsigned int dist=P[t]&0xFFFFu;
    Q[t]=dist?(unsigned int)(LVE-(int)dist):0xFFFFFFFFu;
  }
  __syncthreads();

  // ---- scatter +-1 into P[pos] (P reused as int scan array) ----
  int* scanA=(int*)P;
  for(int t=tid;t<ESLOT;t+=TPR){
    unsigned int pos=Q[t];
    if(pos!=0xFFFFFFFFu){
      int u=t>>2, d=t&3;
      int v=(d==0)?u-1:(d==1)?u+1:(d==2)?u-WW:u+WW;
      unsigned int rpos=Q[(v<<2)|(d^1)];
      scanA[pos]=(pos<rpos)?1:-1;
    }
  }
  __syncthreads();

  // ---- blocked inclusive scan over scanA[0..LVE-1] ----
  const int base=tid*9;
  int vals[9]; int lsum=0;
  #pragma unroll
  for(int j=0;j<9;j++){
    int p=base+j;
    int v=(p<LVE)?scanA[p]:0;
    lsum+=v; vals[j]=lsum;
  }
  chunkS[tid]=lsum;
  __syncthreads();
  for(int off=1;off<TPR;off<<=1){
    int v=chunkS[tid];
    int vv=(tid>=off)?chunkS[tid-off]:0;
    __syncthreads();
    chunkS[tid]=v+vv;
    __syncthreads();
  }
  const int myoff=(tid>0)?chunkS[tid-1]:0;
  int mymax=0;
  #pragma unroll
  for(int j=0;j<9;j++){
    int p=base+j;
    if(p<LVE){ int s=vals[j]+myoff; scanA[p]=s; if(s>mymax) mymax=s; }
  }
  if(mymax>0) atomicMax(&maxdS,mymax);
  __syncthreads();

  // ---- emit per-node records ----
  int* sp=sbase+(size_t)pidx*SSTRIDE_W;
  int4* g_pk=(int4*)(sp+PK_OFF);
  if(tid==0){
    g_pk[0]=make_int4(0,__float_as_int(0.0f),0,0);
    sp[D_OFF]=maxdS;
  }
  for(int t=tid;t<ESLOT;t+=TPR){
    unsigned int pos=Q[t];
    if(pos!=0xFFFFFFFFu){
      int u=t>>2, d=t&3;
      int v=(d==0)?u-1:(d==1)?u+1:(d==2)?u-WW:u+WW;
      unsigned int rpos=Q[(v<<2)|(d^1)];
      if(pos<rpos){                       // down edge: u = parent(v)
        float4 w4=adjwS[u];
        float w=(d==0)?w4.x:(d==1)?w4.y:(d==2)?w4.z:w4.w;
        g_pk[v]=make_int4(u,__float_as_int(w),scanA[pos],0);
      }
    }
  }
}

// ---------------------------------------------------------------------------
// Pointer-doubling tree filter core (upward scatter + downward affine compose).
// Each of TPF=256 lanes owns NPL=9 nodes i = tid + j*256.  All per-node state
// in registers (loops fully unrolled -> static indexing).
// ---------------------------------------------------------------------------
#define FILTER_CORE(X_LOAD)                                                     \
  const int tid=threadIdx.x;                                                    \
  const int maxD=sp[D_OFF];                                                     \
  int T=1; while((1<<T)<=maxD) T++;                                             \
  int parR[NPL]; float wR[NPL]; int depR[NPL];                                  \
  int ancR[NPL]; float prodR[NPL];                                              \
  const int4* g_pk=(const int4*)(sp+PK_OFF);                                    \
  _Pragma("unroll")                                                             \
  for(int j=0;j<NPL;j++){                                                       \
    int i=tid+j*TPF;                                                            \
    int4 rec=g_pk[i];                                                           \
    parR[j]=rec.x; wR[j]=__int_as_float(rec.y); depR[j]=rec.z;                  \
    ancR[j]=parR[j]; prodR[j]=wR[j];                                            \
    ancL[0][i]=parR[j]; prodL[0][i]=wR[j];                                      \
  }                                                                             \
  { X_LOAD }                                                                    \
  __syncthreads();                                                              \
  /* ---- upward: ascending-jump two-phase scatter ---- */                      \
  int ping=0;                                                                   \
  for(int t=0;t<T;t++){                                                         \
    float s0[NPL],s1[NPL],s2[NPL],s3[NPL],s4[NPL];                              \
    _Pragma("unroll")                                                           \
    for(int j=0;j<NPL;j++){                                                     \
      int i=tid+j*TPF;                                                          \
      s0[j]=S[i]; s1[j]=S[NN+i]; s2[j]=S[2*NN+i];                               \
      s3[j]=S[3*NN+i]; s4[j]=S[4*NN+i];                                         \
    }                                                                           \
    __syncthreads();                                                            \
    _Pragma("unroll")                                                           \
    for(int j=0;j<NPL;j++){                                                     \
      int i=tid+j*TPF;                                                          \
      int a=ancR[j];                                                            \
      if(depR[j]>=(1<<t)){                                                      \
        float pw=prodR[j];                                                      \
        atomicAdd(&S[a],      pw*s0[j]);                                        \
        atomicAdd(&S[NN+a],   pw*s1[j]);                                        \
        atomicAdd(&S[2*NN+a], pw*s2[j]);                                        \
        atomicAdd(&S[3*NN+a], pw*s3[j]);                                        \
        atomicAdd(&S[4*NN+a], pw*s4[j]);                                        \
      }                                                                         \
      int a2=ancL[ping][a]; float p2=prodL[ping][a];                            \
      ancR[j]=a2; prodR[j]*=p2;                                                 \
      ancL[1-ping][i]=a2; prodL[1-ping][i]=prodR[j];                            \
    }                                                                           \
    __syncthreads();                                                            \
    ping^=1;                                                                    \
  }                                                                             \
  /* ---- downward: affine (a,b) composition doubling ---- */                   \
  float b0[NPL],b1[NPL],b2[NPL],b3[NPL],b4[NPL]; float aR[NPL];                 \
  _Pragma("unroll")                                                             \
  for(int j=0;j<NPL;j++){                                                       \
    int i=tid+j*TPF;                                                            \
    float w=wR[j]; float fq=1.0f-w*w;                                           \
    b0[j]=fq*S[i]; b1[j]=fq*S[NN+i]; b2[j]=fq*S[2*NN+i];                        \
    b3[j]=fq*S[3*NN+i]; b4[j]=fq*S[4*NN+i];                                     \
    aR[j]=w; ancR[j]=parR[j];                                                   \
    ancL[0][i]=parR[j]; prodL[0][i]=w;                                          \
  }                                                                             \
  __syncthreads();                                                              \
  _Pragma("unroll")                                                             \
  for(int j=0;j<NPL;j++){                                                       \
    int i=tid+j*TPF;                                                            \
    S[i]=b0[j]; S[NN+i]=b1[j]; S[2*NN+i]=b2[j];                                 \
    S[3*NN+i]=b3[j]; S[4*NN+i]=b4[j];                                           \
  }                                                                             \
  __syncthreads();                                                              \
  ping=0;                                                                       \
  for(int t=0;t<T;t++){                                                         \
    float* bfP = ping? bFB : S;                                                 \
    float* bfQ = ping? S : bFB;                                                 \
    _Pragma("unroll")                                                           \
    for(int j=0;j<NPL;j++){                                                     \
      int i=tid+j*TPF;                                                          \
      int a=ancR[j];                                                            \
      float aa=prodL[ping][a];                                                  \
      int   a2=ancL[ping][a];                                                   \
      float t0=bfP[a],t1=bfP[NN+a],t2=bfP[2*NN+a],t3=bfP[3*NN+a],t4=bfP[4*NN+a];\
      b0[j]=fmaf(aR[j],t0,b0[j]); b1[j]=fmaf(aR[j],t1,b1[j]);                   \
      b2[j]=fmaf(aR[j],t2,b2[j]); b3[j]=fmaf(aR[j],t3,b3[j]);                   \
      b4[j]=fmaf(aR[j],t4,b4[j]);                                               \
      aR[j]*=aa; ancR[j]=a2;                                                    \
      bfQ[i]=b0[j]; bfQ[NN+i]=b1[j]; bfQ[2*NN+i]=b2[j];                         \
      bfQ[3*NN+i]=b3[j]; bfQ[4*NN+i]=b4[j];                                     \
      ancL[1-ping][i]=a2; prodL[1-ping][i]=aR[j];                               \
    }                                                                           \
    __syncthreads();                                                            \
    ping^=1;                                                                    \
  }                                                                             \
  float* bfP = ping? bFB : S;                                                   \
  float r0=bfP[0],r1=bfP[NN],r2=bfP[2*NN],r3=bfP[3*NN],r4=bfP[4*NN];

// ---------------------------------------------------------------------------
__global__ __launch_bounds__(TPF) void k_filter0(
  const float* __restrict__ probf, const int* __restrict__ sbase,
  float* __restrict__ AS)
{
  __shared__ float S[5*NN];      // 46080 B (x -> A_up -> bF ping)
  __shared__ float bFB[5*NN];    // 46080 B (bF pong)
  __shared__ int   ancL[2][NN];  // 18432 B
  __shared__ float prodL[2][NN]; // 18432 B
  const int b=blockIdx.x;
  const int* sp=sbase+(size_t)b*SSTRIDE_W;
  FILTER_CORE(
    const float4* pf4=(const float4*)(probf+(size_t)b*KK*NN);
    float4* S4=(float4*)S;
    for(int t2=tid;t2<(KK*NN)/4;t2+=TPF) S4[t2]=pf4[t2];
    for(int t2=KK*NN+tid;t2<5*NN;t2+=TPF) S[t2]=1.0f;
  )
  #pragma unroll
  for(int j=0;j<NPL;j++){
    int i=tid+j*TPF;
    float F0=fmaf(aR[j],r0,b0[j]);
    float F1=fmaf(aR[j],r1,b1[j]);
    float F2=fmaf(aR[j],r2,b2[j]);
    float F3=fmaf(aR[j],r3,b3[j]);
    float F4=fmaf(aR[j],r4,b4[j]);
    float inv=1.0f/F4;
    float* o=AS+(size_t)b*KK*NN;
    o[i]=F0*inv; o[NN+i]=F1*inv; o[2*NN+i]=F2*inv; o[3*NN+i]=F3*inv;
  }
}

// ---------------------------------------------------------------------------
__global__ __launch_bounds__(TPF) void k_filter123(
  const float* __restrict__ AS, const float* __restrict__ probf,
  const float* __restrict__ rois, const int* __restrict__ sbase,
  float* __restrict__ partials)
{
  __shared__ float S[5*NN];
  __shared__ float bFB[5*NN];
  __shared__ int   ancL[2][NN];
  __shared__ float prodL[2][NN];
  __shared__ float red[TPF];
  const int fm1=blockIdx.x/BB, b=blockIdx.x%BB;
  const int pidx=(fm1+1)*BB+b;
  const int* sp=sbase+(size_t)pidx*SSTRIDE_W;
  FILTER_CORE(
    const float4* pf4=(const float4*)(AS+(size_t)b*KK*NN);
    float4* S4=(float4*)S;
    for(int t2=tid;t2<(KK*NN)/4;t2+=TPF) S4[t2]=pf4[t2];
    for(int t2=KK*NN+tid;t2<5*NN;t2+=TPF) S[t2]=1.0f;
  )
  float part=0.0f;
  #pragma unroll
  for(int j=0;j<NPL;j++){
    int i=tid+j*TPF;
    int r=i/WW, c2=i-r*WW;
    float roi=rois[(size_t)b*(192*192)+(4*r)*192+(4*c2)];
    float F4=fmaf(aR[j],r4,b4[j]);
    float inv=1.0f/F4;
    const float* pb=probf+(size_t)b*KK*NN;
    float s=fabsf(pb[i]       - fmaf(aR[j],r0,b0[j])*inv)
          + fabsf(pb[NN+i]    - fmaf(aR[j],r1,b1[j])*inv)
          + fabsf(pb[2*NN+i]  - fmaf(aR[j],r2,b2[j])*inv)
          + fabsf(pb[3*NN+i]  - fmaf(aR[j],r3,b3[j])*inv);
    part+=roi*s;
  }
  red[tid]=part; __syncthreads();
  for(int s2=TPF/2;s2>0;s2>>=1){ if(tid<s2) red[tid]+=red[tid+s2]; __syncthreads(); }
  if(tid==0) partials[blockIdx.x]=red[0];
}

// ---------------------------------------------------------------------------
__global__ __launch_bounds__(TPB) void k_final(const float* __restrict__ rois,
    const float* __restrict__ partials, const float* __restrict__ wt,
    float* __restrict__ out)
{
  __shared__ float red[TPB];
  const int tid=threadIdx.x;
  float n=0.0f;
  for(int t=tid;t<BB*NN;t+=TPB){
    int b=t/NN, i=t-b*NN; int r=i/WW, c=i-r*WW;
    n += rois[(size_t)b*(192*192)+(4*r)*192+(4*c)];
  }
  red[tid]=n; __syncthreads();
  for(int s=TPB/2;s>0;s>>=1){ if(tid<s) red[tid]+=red[tid+s]; __syncthreads(); }
  if(tid==0){
    float loss=0.0f;
    for(int j=0;j<3*BB;j++) loss+=partials[j];
    float N=red[0];
    out[0]=wt[0]*((N>0.0f)?(loss/N):loss);
  }
}

// ---------------------------------------------------------------------------
extern "C" void kernel_launch(void* const* d_in, const int* in_sizes, int n_in,
                              void* d_out, int out_size, void* d_ws, size_t ws_size,
                              hipStream_t stream) {
  (void)in_sizes; (void)n_in; (void)out_size;
  const float* preds=(const float*)d_in[0];
  const float* lowf =(const float*)d_in[1];
  const float* hf1  =(const float*)d_in[2];
  const float* hf2  =(const float*)d_in[3];
  const float* hf3  =(const float*)d_in[4];
  const float* rois =(const float*)d_in[5];
  const float* wt   =(const float*)d_in[6];
  float* out=(float*)d_out;

  char* ws=(char*)d_ws;
  float* partials=(float*)ws;                                  // 24 floats @0
  float* probf=(float*)(ws+256);                               // 294912 B
  float* AS   =(float*)(ws+256+(size_t)BB*KK*NN*4);            // 294912 B
  size_t sb_off=256+(size_t)2*BB*KK*NN*4;                      // 590080
  int*   sbase=(int*)(ws+sb_off);                              // 32*SSTRIDE_W*4 = 1180672 B
  size_t aw_off=sb_off+(size_t)32*SSTRIDE_W*4;                 // 1770752
  float4* adjwG=(float4*)(ws+aw_off);                          // 32*NN*16 = 1179648 B
  size_t aj_off=aw_off+(size_t)32*NN*16;                       // 2950400
  unsigned char* adjG=(unsigned char*)(ws+aj_off);             // 32*NN = 73728 B
  size_t pd_off=aj_off+(size_t)32*NN;                          // 3024128 (8-mult)
  double* pd=(double*)(ws+pd_off);

  int nchunk=16;
  while(nchunk>1 && pd_off+(size_t)32*nchunk*EEE*8>ws_size) nchunk>>=1;

  k_prob<<<(BB*NN+TPB-1)/TPB,TPB,0,stream>>>(preds,probf);
  k_edges<<<8+24*nchunk,TPB,0,stream>>>(lowf,hf1,hf2,hf3,pd,nchunk);
  k_boruvka<<<32,TPW,0,stream>>>(pd,nchunk,adjwG,adjG);
  k_root<<<32,TPR,0,stream>>>(adjwG,adjG,sbase);
  k_filter0<<<BB,TPF,0,stream>>>(probf,sbase,AS);
  k_filter123<<<3*BB,TPF,0,stream>>>(AS,probf,rois,sbase,partials);
  k_final<<<1,TPB,0,stream>>>(rois,partials,wt,out);
}